// Round 8
// baseline (251.340 us; speedup 1.0000x reference)
//
#include <hip/hip_runtime.h>
#include <math.h>

#define BB 131072
#define HH 64
#define NOB 32
#define NDIRS 8
#define LR_IT 1e-3f
#define TOLV 1e-3f
#define EPSV 1e-6f
#define NBLK 512
#define TPB 256
#define WIS 68   // LDS row stride (floats) for WinT (only remaining LDS table)
#define INV_BH (1.0f/8388608.0f)   // 1/(B*H)

// macro params must not be named x/y/z/w (textual expansion vs .x/.y/.z/.w members)
#define DG4(pp, fv) ((pp).x*(fv).x + (pp).y*(fv).y + (pp).z*(fv).z + (pp).w*(fv).w)
// dot64 of register row p0..p15 with a wave-UNIFORM global row (float4*): the
// weight loads have no threadIdx dependence -> compiler emits s_load + FMAs
// with the scalar operand, keeping them off the LDS/VMEM vector pipes.
#define DOT64G(W4) (DG4(p0,(W4)[0])+DG4(p1,(W4)[1])+DG4(p2,(W4)[2])+DG4(p3,(W4)[3])+ \
                    DG4(p4,(W4)[4])+DG4(p5,(W4)[5])+DG4(p6,(W4)[6])+DG4(p7,(W4)[7])+ \
                    DG4(p8,(W4)[8])+DG4(p9,(W4)[9])+DG4(p10,(W4)[10])+DG4(p11,(W4)[11])+ \
                    DG4(p12,(W4)[12])+DG4(p13,(W4)[13])+DG4(p14,(W4)[14])+DG4(p15,(W4)[15]))
#define LOADP(src) \
  float4 p0=(src)[0], p1=(src)[1], p2=(src)[2], p3=(src)[3], \
         p4=(src)[4], p5=(src)[5], p6=(src)[6], p7=(src)[7], \
         p8=(src)[8], p9=(src)[9], p10=(src)[10], p11=(src)[11], \
         p12=(src)[12], p13=(src)[13], p14=(src)[14], p15=(src)[15];
#define SUMSQ4(pp) ((pp).x*(pp).x + (pp).y*(pp).y + (pp).z*(pp).z + (pp).w*(pp).w)
#define SUM4(pp) ((pp).x + (pp).y + (pp).z + (pp).w)

__device__ __forceinline__ void stage_wint(const float* __restrict__ Win, float* wint, int t) {
  for (int i = t; i < HH * NDIRS; i += TPB) {    // Win [64][8] -> wint[d][h]
    int h = i >> 3, d = i & 7;
    wint[d * WIS + h] = Win[i];
  }
}

// wave-shuffle + LDS block reduction; returns block total to ALL threads.
__device__ __forceinline__ float block_reduce_all(float v, float* red, int t) {
  #pragma unroll
  for (int off = 32; off > 0; off >>= 1) v += __shfl_down(v, off);
  __syncthreads();                   // guard red[] from any previous use
  if ((t & 63) == 0) red[t >> 6] = v;
  __syncthreads();
  return red[0] + red[1] + red[2] + red[3];
}

// ---- prep: transpose Wout[32][64] -> wotT[64][32] (ws), so all later weight
//      reads are row-contiguous uniform loads ----
__global__ __launch_bounds__(TPB) void prep_kernel(
    const float* __restrict__ Wout, float* __restrict__ wotT)
{
  int i = blockIdx.x * TPB + threadIdx.x;
  if (i < NOB * HH) {
    int h = i >> 5, o = i & 31;
    wotT[i] = Wout[o * HH + h];
  }
}

// preds = softmax(a_s * S_raw @ wotT^T-ish) -> out[:B*32]; a_s*S_raw -> out[B*32:]
__device__ __forceinline__ void final_write(
    int r, float a_s, const float* __restrict__ S, float* __restrict__ out,
    const float* __restrict__ wotT) {
  const float4* __restrict__ sr4 = (const float4*)(S + (size_t)r * HH);
  float zz[NOB];
  #pragma unroll
  for (int o = 0; o < NOB; ++o) zz[o] = 0.f;
  #pragma unroll 1
  for (int h0 = 0; h0 < 16; ++h0) {
    float4 s4 = sr4[h0];
    const float4* t0 = (const float4*)(wotT + (h0 * 4 + 0) * NOB);
    const float4* t1 = (const float4*)(wotT + (h0 * 4 + 1) * NOB);
    const float4* t2 = (const float4*)(wotT + (h0 * 4 + 2) * NOB);
    const float4* t3 = (const float4*)(wotT + (h0 * 4 + 3) * NOB);
    #pragma unroll
    for (int o4 = 0; o4 < 8; ++o4) {
      float4 w0 = t0[o4], w1 = t1[o4], w2 = t2[o4], w3 = t3[o4];
      zz[o4*4+0] += s4.x*w0.x + s4.y*w1.x + s4.z*w2.x + s4.w*w3.x;
      zz[o4*4+1] += s4.x*w0.y + s4.y*w1.y + s4.z*w2.y + s4.w*w3.y;
      zz[o4*4+2] += s4.x*w0.z + s4.y*w1.z + s4.z*w2.z + s4.w*w3.z;
      zz[o4*4+3] += s4.x*w0.w + s4.y*w1.w + s4.z*w2.w + s4.w*w3.w;
    }
  }
  float m = -1e30f;
  #pragma unroll
  for (int o = 0; o < NOB; ++o) m = fmaxf(m, zz[o]);
  float se = 0.f;
  #pragma unroll
  for (int o = 0; o < NOB; ++o) { zz[o] = __expf(a_s * (zz[o] - m)); se += zz[o]; }
  float rse = 1.f / se;

  float4* po = (float4*)(out + (size_t)r * NOB);
  #pragma unroll
  for (int o4 = 0; o4 < 8; ++o4) {
    float4 f;
    f.x = zz[o4 * 4 + 0] * rse; f.y = zz[o4 * 4 + 1] * rse;
    f.z = zz[o4 * 4 + 2] * rse; f.w = zz[o4 * 4 + 3] * rse;
    po[o4] = f;
  }
  float4* so = (float4*)(out + (size_t)BB * NOB + (size_t)r * HH);
  #pragma unroll 1
  for (int h0 = 0; h0 < 16; ++h0) {
    float4 s4 = sr4[h0];    // in-place safe: same thread reads then writes same addr
    s4.x *= a_s; s4.y *= a_s; s4.z *= a_s; s4.w *= a_s;
    so[h0] = s4;
  }
}

// ---- init: prev=norm(x) implicit (x + sclX); s0 raw -> buf0, scale -> scl0 ----
__global__ __launch_bounds__(TPB, 2) void init_kernel(
    const float* __restrict__ x, const int* __restrict__ dirs,
    const float* __restrict__ Wr, const float* __restrict__ Win,
    float* __restrict__ buf0, float* __restrict__ sclX, float* __restrict__ scl0,
    float* __restrict__ partials)
{
  __shared__ float wint[NDIRS * WIS];
  __shared__ float red[4];
  int t = threadIdx.x;
  stage_wint(Win, wint, t);
  __syncthreads();

  int r = blockIdx.x * TPB + t;
  const float4* __restrict__ xr = (const float4*)(x + (size_t)r * HH);
  LOADP(xr);

  float ssx = SUMSQ4(p0)+SUMSQ4(p1)+SUMSQ4(p2)+SUMSQ4(p3)+SUMSQ4(p4)+SUMSQ4(p5)+
              SUMSQ4(p6)+SUMSQ4(p7)+SUMSQ4(p8)+SUMSQ4(p9)+SUMSQ4(p10)+SUMSQ4(p11)+
              SUMSQ4(p12)+SUMSQ4(p13)+SUMSQ4(p14)+SUMSQ4(p15);
  float sx  = SUM4(p0)+SUM4(p1)+SUM4(p2)+SUM4(p3)+SUM4(p4)+SUM4(p5)+SUM4(p6)+SUM4(p7)+
              SUM4(p8)+SUM4(p9)+SUM4(p10)+SUM4(p11)+SUM4(p12)+SUM4(p13)+SUM4(p14)+SUM4(p15);
  float inv_x = 1.f / (sqrtf(ssx) + EPSV);
  int dir = dirs[r];

  float4* bo = (float4*)(buf0 + (size_t)r * HH);
  float ssg = 0.f, sg = 0.f;
#define INIT_ONE(JJ, COMP) { \
    const float4* wr4_ = (const float4*)(Wr + (h0 * 4 + JJ) * HH); \
    u.COMP = fmaxf(fmaf(inv_x, DOT64G(wr4_), d4.COMP), 0.f); }
  #pragma unroll 1
  for (int h0 = 0; h0 < 16; ++h0) {
    float4 d4 = *(const float4*)&wint[dir * WIS + h0 * 4];
    float4 u;
    INIT_ONE(0, x) INIT_ONE(1, y) INIT_ONE(2, z) INIT_ONE(3, w)
    bo[h0] = u;
    ssg += SUMSQ4(u); sg += SUM4(u);
  }
  float inv_g = 1.f / (sqrtf(ssg) + EPSV);
  sclX[r] = inv_x;
  scl0[r] = inv_g;

  float tot = block_reduce_all(inv_x * sx - inv_g * sg, red, t);
  if (t == 0) partials[blockIdx.x] = tot;
}

// ---- launch k: gate + (active step | first-inactive final-write | no-op) ----
// Sticky gate => at any launch that is active or first-inactive, #prior-active == k.
__global__ __launch_bounds__(TPB, 2) void step_kernel(
    const float* __restrict__ x,
    float* __restrict__ buf0, float* __restrict__ buf1,
    const float* __restrict__ sclX, float* __restrict__ scl0, float* __restrict__ scl1,
    const float* __restrict__ Wr, const float* __restrict__ wotT, const float* __restrict__ Win,
    const int* __restrict__ dirs, const int* __restrict__ obs,
    float* __restrict__ partials, int* __restrict__ actArr,
    float* __restrict__ out, int k)
{
  __shared__ float red[4];
  __shared__ float wint[NDIRS * WIS];
  int t = threadIdx.x;

  // gate: every block reduces the identical 512 partials -> uniform decision
  float tot = block_reduce_all(partials[t] + partials[t + TPB], red, t);
  int active = (fabsf(tot * INV_BH) > TOLV) ? 1 : 0;
  if (blockIdx.x == 0 && t == 0) actArr[k] = active;

  int si = k & 1;
  int r = blockIdx.x * TPB + t;

  if (!active) {
    int first_inactive = (k == 0) ? 1 : actArr[k - 1];   // written by previous launch
    if (!first_inactive) return;                          // uniform across grid
    const float* S   = si ? buf1 : buf0;
    const float* scl = si ? scl1 : scl0;
    final_write(r, scl[r], S, out, wotT);
    return;
  }

  const float* S    = si ? buf1 : buf0;
  const float* sclS = si ? scl1 : scl0;
  float* W          = si ? buf0 : buf1;          // prev slot, overwritten with new s
  float* sclW       = si ? scl0 : scl1;
  const float* P    = (k == 0) ? x    : W;       // prev state rows (this thread's own)
  const float* sclP = (k == 0) ? sclX : sclW;

  stage_wint(Win, wint, t);
  __syncthreads();

  float a_s = sclS[r];
  float a_p = sclP[r];
  int ob = obs[r];
  int dir = dirs[r];
  const float4* __restrict__ sr4 = (const float4*)(S + (size_t)r * HH);

  // ---- phase A: logits (raw scale); weights = uniform contiguous wotT rows ----
  float zz[NOB];
  #pragma unroll
  for (int o = 0; o < NOB; ++o) zz[o] = 0.f;
  float sS = 0.f;
  #pragma unroll 1
  for (int h0 = 0; h0 < 16; ++h0) {
    float4 s4 = sr4[h0];
    sS += SUM4(s4);
    const float4* t0 = (const float4*)(wotT + (h0 * 4 + 0) * NOB);
    const float4* t1 = (const float4*)(wotT + (h0 * 4 + 1) * NOB);
    const float4* t2 = (const float4*)(wotT + (h0 * 4 + 2) * NOB);
    const float4* t3 = (const float4*)(wotT + (h0 * 4 + 3) * NOB);
    #pragma unroll
    for (int o4 = 0; o4 < 8; ++o4) {
      float4 w0 = t0[o4], w1 = t1[o4], w2 = t2[o4], w3 = t3[o4];
      zz[o4*4+0] += s4.x*w0.x + s4.y*w1.x + s4.z*w2.x + s4.w*w3.x;
      zz[o4*4+1] += s4.x*w0.y + s4.y*w1.y + s4.z*w2.y + s4.w*w3.y;
      zz[o4*4+2] += s4.x*w0.z + s4.y*w1.z + s4.z*w2.z + s4.w*w3.z;
      zz[o4*4+3] += s4.x*w0.w + s4.y*w1.w + s4.z*w2.w + s4.w*w3.w;
    }
  }

  // softmax (max commutes with positive scale a_s), then zz -> jp in place
  float m = -1e30f;
  #pragma unroll
  for (int o = 0; o < NOB; ++o) m = fmaxf(m, zz[o]);
  float se = 0.f;
  #pragma unroll
  for (int o = 0; o < NOB; ++o) { zz[o] = __expf(a_s * (zz[o] - m)); se += zz[o]; }
  float rse = 1.f / se;
  float fob = 0.f, sf2 = 0.f;
  #pragma unroll
  for (int o = 0; o < NOB; ++o) {
    float f = zz[o] * rse;
    zz[o] = f;
    sf2 += f * f;
    fob += (o == ob) ? f : 0.f;
  }
  float fe = fob - sf2;
  #pragma unroll
  for (int o = 0; o < NOB; ++o) {
    float ep = ((o == ob) ? 1.f : 0.f) - zz[o];
    zz[o] = zz[o] * (ep - fe);   // jp
  }

  __syncthreads();   // live-range firewall: P row enters registers only after phase A

  // ---- phase B+C fused: u = s + LR*(relu(a_p*dot64(P,Wr_h)+drive_h) - s + dot32(jp,wotT_h)) ----
  const float4* __restrict__ pr4 = (const float4*)(P + (size_t)r * HH);
  LOADP(pr4);
  float4* wo4 = (float4*)(W + (size_t)r * HH);
  float ssu = 0.f, su = 0.f;
#define STEP_C_ONE(JJ, COMP) { \
    const float4* wr4_ = (const float4*)(Wr + (h0 * 4 + JJ) * HH); \
    float g_ = fmaxf(fmaf(a_p, DOT64G(wr4_), d4.COMP), 0.f); \
    const float4* wt4_ = (const float4*)(wotT + (h0 * 4 + JJ) * NOB); \
    float w_ = 0.f; \
    _Pragma("unroll") \
    for (int o4 = 0; o4 < 8; ++o4) { float4 wv = wt4_[o4]; \
      w_ += zz[o4*4+0]*wv.x + zz[o4*4+1]*wv.y + zz[o4*4+2]*wv.z + zz[o4*4+3]*wv.w; } \
    float sv_ = a_s * s4.COMP; \
    float uu_ = fmaf(LR_IT, g_ - sv_ + w_, sv_); \
    u.COMP = uu_; ssu += uu_ * uu_; su += uu_; }
  #pragma unroll 1
  for (int h0 = 0; h0 < 16; ++h0) {
    float4 s4 = sr4[h0];
    float4 d4 = *(const float4*)&wint[dir * WIS + h0 * 4];
    float4 u;
    STEP_C_ONE(0, x) STEP_C_ONE(1, y) STEP_C_ONE(2, z) STEP_C_ONE(3, w)
    wo4[h0] = u;
  }
  float inv_u = 1.f / (sqrtf(ssu) + EPSV);
  sclW[r] = inv_u;

  float tot2 = block_reduce_all(a_s * sS - inv_u * su, red, t);
  if (t == 0) partials[blockIdx.x] = tot2;
}

// ---- tail: only fires when all 10 steps were active ----
__global__ __launch_bounds__(TPB, 2) void final_kernel(
    const float* __restrict__ buf0, float* __restrict__ out,
    const float* __restrict__ scl0,
    const float* __restrict__ wotT, const int* __restrict__ actArr)
{
  if (actArr[9] == 0) return;          // uniform: final already written by first-inactive step
  // 10 active steps: s10 lives in buf0/scl0 (parity 10&1==0)
  int r = blockIdx.x * TPB + threadIdx.x;
  final_write(r, scl0[r], buf0, out, wotT);
}

extern "C" void kernel_launch(void* const* d_in, const int* in_sizes, int n_in,
                              void* d_out, int out_size, void* d_ws, size_t ws_size,
                              hipStream_t stream) {
  const int* dirs = (const int*)d_in[0];
  const int* obs = (const int*)d_in[1];
  const float* x = (const float*)d_in[2];
  const float* Wr = (const float*)d_in[3];
  const float* Win = (const float*)d_in[4];
  const float* Wout = (const float*)d_in[5];
  float* out = (float*)d_out;
  float* ws = (float*)d_ws;

  float* buf0 = ws;                              // B*H raw state
  float* sclX = ws + (size_t)BB * HH;            // B
  float* scl0 = sclX + BB;                       // B
  float* scl1 = scl0 + BB;                       // B
  float* partials = scl1 + BB;                   // NBLK
  int* actArr = (int*)(partials + NBLK);         // 10 ints
  float* wotT = (float*)(actArr + 16);           // 64*32 transposed Wout
  float* buf1 = out + (size_t)BB * NOB;          // s-slice of d_out doubles as state

  prep_kernel<<<(NOB * HH + TPB - 1) / TPB, TPB, 0, stream>>>(Wout, wotT);
  init_kernel<<<NBLK, TPB, 0, stream>>>(x, dirs, Wr, Win, buf0, sclX, scl0, partials);
  for (int k = 0; k < 10; ++k)
    step_kernel<<<NBLK, TPB, 0, stream>>>(x, buf0, buf1, sclX, scl0, scl1,
                                          Wr, wotT, Win, dirs, obs, partials, actArr, out, k);
  final_kernel<<<NBLK, TPB, 0, stream>>>(buf0, out, scl0, wotT, actArr);
}

// Round 9
// 172.945 us; speedup vs baseline: 1.4533x; 1.4533x over previous
//
#include <hip/hip_runtime.h>
#include <math.h>

#define BB 131072
#define HH 64
#define NOB 32
#define NDIRS 8
#define LR_IT 1e-3f
#define TOLV 1e-3f
#define EPSV 1e-6f
#define NBLK 512
#define TPB 256
#define TPB0 128  // step0 block size (2 rows/thread)
#define WRS 68   // LDS row stride (floats) for Wr / WinT
#define WOS 36   // LDS row stride for WoutT
#define INV_BH (1.0f/8388608.0f)   // 1/(B*H)

// macro params must not be named x/y/z/w (textual expansion vs .x/.y/.z/.w members)
#define D16(pp, Wp, b) ((pp).x*(Wp)[(b)+0] + (pp).y*(Wp)[(b)+1] + (pp).z*(Wp)[(b)+2] + (pp).w*(Wp)[(b)+3])
#define DOT64P(Wp) (D16(p0,Wp,0)+D16(p1,Wp,4)+D16(p2,Wp,8)+D16(p3,Wp,12)+ \
                    D16(p4,Wp,16)+D16(p5,Wp,20)+D16(p6,Wp,24)+D16(p7,Wp,28)+ \
                    D16(p8,Wp,32)+D16(p9,Wp,36)+D16(p10,Wp,40)+D16(p11,Wp,44)+ \
                    D16(p12,Wp,48)+D16(p13,Wp,52)+D16(p14,Wp,56)+D16(p15,Wp,60))
#define LOADP(src) \
  float4 p0=(src)[0], p1=(src)[1], p2=(src)[2], p3=(src)[3], \
         p4=(src)[4], p5=(src)[5], p6=(src)[6], p7=(src)[7], \
         p8=(src)[8], p9=(src)[9], p10=(src)[10], p11=(src)[11], \
         p12=(src)[12], p13=(src)[13], p14=(src)[14], p15=(src)[15];
#define SUMSQ4(pp) ((pp).x*(pp).x + (pp).y*(pp).y + (pp).z*(pp).z + (pp).w*(pp).w)
#define SUM4(pp) ((pp).x + (pp).y + (pp).z + (pp).w)

// ---- LDS staging (stride = blockDim) ----
__device__ __forceinline__ void stage_wr(const float* __restrict__ Wr, float* wrl, int t, int bs) {
  const float4* g = (const float4*)Wr;           // Wr row-major [64][64]
  for (int i = t; i < 1024; i += bs) {
    int h = i >> 4, k4 = i & 15;
    *(float4*)&wrl[h * WRS + k4 * 4] = g[i];
  }
}
__device__ __forceinline__ void stage_wot(const float* __restrict__ Wout, float* wot, int t, int bs) {
  for (int i = t; i < NOB * HH; i += bs) {       // Wout [32][64] -> wot[h][o]
    int o = i >> 6, h = i & 63;
    wot[h * WOS + o] = Wout[i];
  }
}
__device__ __forceinline__ void stage_wint(const float* __restrict__ Win, float* wint, int t, int bs) {
  for (int i = t; i < HH * NDIRS; i += bs) {     // Win [64][8] -> wint[d][h]
    int h = i >> 3, d = i & 7;
    wint[d * WRS + h] = Win[i];
  }
}

// 256-thread (4-wave) block reduction; returns block total to ALL threads.
__device__ __forceinline__ float block_reduce_all(float v, float* red, int t) {
  #pragma unroll
  for (int off = 32; off > 0; off >>= 1) v += __shfl_down(v, off);
  __syncthreads();
  if ((t & 63) == 0) red[t >> 6] = v;
  __syncthreads();
  return red[0] + red[1] + red[2] + red[3];
}
// 128-thread (2-wave) variant
__device__ __forceinline__ float block_reduce_all2(float v, float* red, int t) {
  #pragma unroll
  for (int off = 32; off > 0; off >>= 1) v += __shfl_down(v, off);
  __syncthreads();
  if ((t & 63) == 0) red[t >> 6] = v;
  __syncthreads();
  return red[0] + red[1];
}

// softmax(a_s * zz) -> jacobian-applied jp, in place (zz starts as raw logits)
#define SOFTJP(zzp, a_sv, obv) { \
  float m_ = -1e30f; \
  _Pragma("unroll") for (int o_=0;o_<NOB;++o_) m_ = fmaxf(m_, (zzp)[o_]); \
  float se_ = 0.f; \
  _Pragma("unroll") for (int o_=0;o_<NOB;++o_){ (zzp)[o_]=__expf((a_sv)*((zzp)[o_]-m_)); se_+=(zzp)[o_];} \
  float rse_ = 1.f/se_; float fob_=0.f, sf2_=0.f; \
  _Pragma("unroll") for (int o_=0;o_<NOB;++o_){ float f_=(zzp)[o_]*rse_; (zzp)[o_]=f_; sf2_+=f_*f_; fob_ += (o_==(obv))?f_:0.f;} \
  float fe_ = fob_ - sf2_; \
  _Pragma("unroll") for (int o_=0;o_<NOB;++o_){ float ep_=((o_==(obv))?1.f:0.f)-(zzp)[o_]; (zzp)[o_]=(zzp)[o_]*(ep_-fe_);} }

// preds = softmax(a_s * S_raw @ wot) -> out[:B*32]; a_s*S_raw -> out[B*32:]
__device__ __forceinline__ void final_write(
    int r, float a_s, const float* __restrict__ S, float* __restrict__ out,
    const float* wot) {
  const float4* __restrict__ sr4 = (const float4*)(S + (size_t)r * HH);
  float zz[NOB];
  #pragma unroll
  for (int o = 0; o < NOB; ++o) zz[o] = 0.f;
  #pragma unroll 1
  for (int h0 = 0; h0 < 16; ++h0) {
    float4 s4 = sr4[h0];
    const float* t0 = &wot[(h0 * 4 + 0) * WOS];
    const float* t1 = &wot[(h0 * 4 + 1) * WOS];
    const float* t2 = &wot[(h0 * 4 + 2) * WOS];
    const float* t3 = &wot[(h0 * 4 + 3) * WOS];
    #pragma unroll
    for (int o = 0; o < NOB; ++o)
      zz[o] += s4.x * t0[o] + s4.y * t1[o] + s4.z * t2[o] + s4.w * t3[o];
  }
  float m = -1e30f;
  #pragma unroll
  for (int o = 0; o < NOB; ++o) m = fmaxf(m, zz[o]);
  float se = 0.f;
  #pragma unroll
  for (int o = 0; o < NOB; ++o) { zz[o] = __expf(a_s * (zz[o] - m)); se += zz[o]; }
  float rse = 1.f / se;

  float4* po = (float4*)(out + (size_t)r * NOB);
  #pragma unroll
  for (int o4 = 0; o4 < 8; ++o4) {
    float4 f;
    f.x = zz[o4 * 4 + 0] * rse; f.y = zz[o4 * 4 + 1] * rse;
    f.z = zz[o4 * 4 + 2] * rse; f.w = zz[o4 * 4 + 3] * rse;
    po[o4] = f;
  }
  float4* so = (float4*)(out + (size_t)BB * NOB + (size_t)r * HH);
  #pragma unroll 1
  for (int h0 = 0; h0 < 16; ++h0) {
    float4 s4 = sr4[h0];    // in-place safe: same thread reads then writes same addr
    s4.x *= a_s; s4.y *= a_s; s4.z *= a_s; s4.w *= a_s;
    so[h0] = s4;
  }
}

// ---- init: prev=norm(x) implicit (x + sclX); s0 raw -> buf0, scale -> scl0 ----
__global__ __launch_bounds__(TPB, 2) void init_kernel(
    const float* __restrict__ x, const int* __restrict__ dirs,
    const float* __restrict__ Wr, const float* __restrict__ Win,
    float* __restrict__ buf0, float* __restrict__ sclX, float* __restrict__ scl0,
    float* __restrict__ partials)
{
  __shared__ float wrl[HH * WRS];
  __shared__ float wint[NDIRS * WRS];
  __shared__ float red[4];
  int t = threadIdx.x;
  stage_wr(Wr, wrl, t, TPB);
  stage_wint(Win, wint, t, TPB);
  __syncthreads();

  int r = blockIdx.x * TPB + t;
  const float4* __restrict__ xr = (const float4*)(x + (size_t)r * HH);
  LOADP(xr);

  float ssx = SUMSQ4(p0)+SUMSQ4(p1)+SUMSQ4(p2)+SUMSQ4(p3)+SUMSQ4(p4)+SUMSQ4(p5)+
              SUMSQ4(p6)+SUMSQ4(p7)+SUMSQ4(p8)+SUMSQ4(p9)+SUMSQ4(p10)+SUMSQ4(p11)+
              SUMSQ4(p12)+SUMSQ4(p13)+SUMSQ4(p14)+SUMSQ4(p15);
  float sx  = SUM4(p0)+SUM4(p1)+SUM4(p2)+SUM4(p3)+SUM4(p4)+SUM4(p5)+SUM4(p6)+SUM4(p7)+
              SUM4(p8)+SUM4(p9)+SUM4(p10)+SUM4(p11)+SUM4(p12)+SUM4(p13)+SUM4(p14)+SUM4(p15);
  float inv_x = 1.f / (sqrtf(ssx) + EPSV);
  int dir = dirs[r];

  float4* bo = (float4*)(buf0 + (size_t)r * HH);
  float ssg = 0.f, sg = 0.f;
#define INIT_ONE(JJ, COMP) { \
    const float* wr_ = &wrl[(h0 * 4 + JJ) * WRS]; \
    u.COMP = fmaxf(fmaf(inv_x, DOT64P(wr_), d4.COMP), 0.f); }
  #pragma unroll 1
  for (int h0 = 0; h0 < 16; ++h0) {
    float4 d4 = *(const float4*)&wint[dir * WRS + h0 * 4];
    float4 u;
    INIT_ONE(0, x) INIT_ONE(1, y) INIT_ONE(2, z) INIT_ONE(3, w)
    bo[h0] = u;
    ssg += SUMSQ4(u); sg += SUM4(u);
  }
  float inv_g = 1.f / (sqrtf(ssg) + EPSV);
  sclX[r] = inv_x;
  scl0[r] = inv_g;

  float tot = block_reduce_all(inv_x * sx - inv_g * sg, red, t);
  if (t == 0) partials[blockIdx.x] = tot;
}

// ---- step0: k=0 specialization. g = relu(prev@WrT+drive) == raw s0 (stored in
// buf0 by init, bit-identical) -> NO Wr matvec, no P row. 2 rows/thread. ----
__global__ __launch_bounds__(TPB0, 2) void step0_kernel(
    const float* __restrict__ buf0, float* __restrict__ buf1,
    const float* __restrict__ scl0, float* __restrict__ scl1,
    const float* __restrict__ Wout, const int* __restrict__ obs,
    float* __restrict__ partials, int* __restrict__ actArr,
    float* __restrict__ out)
{
  __shared__ float red[2];
  __shared__ float wot[HH * WOS];
  int t = threadIdx.x;

  // gate over the 512 init partials
  float v = partials[t] + partials[t + 128] + partials[t + 256] + partials[t + 384];
  float tot = block_reduce_all2(v, red, t);
  int active = (fabsf(tot * INV_BH) > TOLV) ? 1 : 0;
  if (blockIdx.x == 0 && t == 0) actArr[0] = active;

  stage_wot(Wout, wot, t, TPB0);
  __syncthreads();

  int r0 = blockIdx.x * (TPB0 * 2) + t;
  int r1 = r0 + TPB0;

  if (!active) {   // k=0 is by definition first-inactive: emit final output
    final_write(r0, scl0[r0], buf0, out, wot);
    final_write(r1, scl0[r1], buf0, out, wot);
    return;
  }

  float a_s0 = scl0[r0], a_s1 = scl0[r1];
  int oba = obs[r0], obb = obs[r1];
  const float4* __restrict__ sra = (const float4*)(buf0 + (size_t)r0 * HH);
  const float4* __restrict__ srb = (const float4*)(buf0 + (size_t)r1 * HH);

  // phase A: logits for both rows (raw scale), weights from LDS broadcast
  float zza[NOB], zzb[NOB];
  #pragma unroll
  for (int o = 0; o < NOB; ++o) { zza[o] = 0.f; zzb[o] = 0.f; }
  float sSa = 0.f, sSb = 0.f;
#define A2_ONE(JJ, COMP) { \
    const float4* wt_ = (const float4*)&wot[(h0 * 4 + JJ) * WOS]; \
    float sa_ = a4.COMP, sb_ = b4.COMP; \
    _Pragma("unroll") \
    for (int o4 = 0; o4 < 8; ++o4) { \
      float4 wv = wt_[o4]; \
      zza[o4*4+0] += sa_*wv.x; zza[o4*4+1] += sa_*wv.y; \
      zza[o4*4+2] += sa_*wv.z; zza[o4*4+3] += sa_*wv.w; \
      zzb[o4*4+0] += sb_*wv.x; zzb[o4*4+1] += sb_*wv.y; \
      zzb[o4*4+2] += sb_*wv.z; zzb[o4*4+3] += sb_*wv.w; } }
  #pragma unroll 1
  for (int h0 = 0; h0 < 16; ++h0) {
    float4 a4 = sra[h0];
    float4 b4 = srb[h0];
    sSa += SUM4(a4); sSb += SUM4(b4);
    A2_ONE(0, x) A2_ONE(1, y) A2_ONE(2, z) A2_ONE(3, w)
  }

  SOFTJP(zza, a_s0, oba)
  SOFTJP(zzb, a_s1, obb)

  // phase C: u = s + LR*(g - s + jp@Wout), g = raw buf0 value, s = a_s*g
  float4* woa = (float4*)(buf1 + (size_t)r0 * HH);
  float4* wob = (float4*)(buf1 + (size_t)r1 * HH);
  float ssua = 0.f, sua = 0.f, ssub = 0.f, sub = 0.f;
#define C2_ONE(JJ, COMP) { \
    const float4* wt_ = (const float4*)&wot[(h0 * 4 + JJ) * WOS]; \
    float wa_ = 0.f, wb_ = 0.f; \
    _Pragma("unroll") \
    for (int o4 = 0; o4 < 8; ++o4) { \
      float4 wv = wt_[o4]; \
      wa_ += zza[o4*4+0]*wv.x + zza[o4*4+1]*wv.y + zza[o4*4+2]*wv.z + zza[o4*4+3]*wv.w; \
      wb_ += zzb[o4*4+0]*wv.x + zzb[o4*4+1]*wv.y + zzb[o4*4+2]*wv.z + zzb[o4*4+3]*wv.w; } \
    float ga_ = a4.COMP, gb_ = b4.COMP; \
    float sva_ = a_s0 * ga_, svb_ = a_s1 * gb_; \
    float uua_ = fmaf(LR_IT, ga_ - sva_ + wa_, sva_); \
    float uub_ = fmaf(LR_IT, gb_ - svb_ + wb_, svb_); \
    ua.COMP = uua_; ub.COMP = uub_; \
    ssua += uua_*uua_; sua += uua_; ssub += uub_*uub_; sub += uub_; }
  #pragma unroll 1
  for (int h0 = 0; h0 < 16; ++h0) {
    float4 a4 = sra[h0];
    float4 b4 = srb[h0];
    float4 ua, ub;
    C2_ONE(0, x) C2_ONE(1, y) C2_ONE(2, z) C2_ONE(3, w)
    woa[h0] = ua;
    wob[h0] = ub;
  }
  float inv_ua = 1.f / (sqrtf(ssua) + EPSV);
  float inv_ub = 1.f / (sqrtf(ssub) + EPSV);
  scl1[r0] = inv_ua;
  scl1[r1] = inv_ub;

  float contrib = a_s0 * sSa - inv_ua * sua + a_s1 * sSb - inv_ub * sub;
  float tot2 = block_reduce_all2(contrib, red, t);
  if (t == 0) partials[blockIdx.x] = tot2;
}

// ---- generic step k>=1 (LDS weights): gate + (active | first-inactive final | no-op) ----
__global__ __launch_bounds__(TPB, 2) void step_kernel(
    const float* __restrict__ x,
    float* __restrict__ buf0, float* __restrict__ buf1,
    const float* __restrict__ sclX, float* __restrict__ scl0, float* __restrict__ scl1,
    const float* __restrict__ Wr, const float* __restrict__ Wout, const float* __restrict__ Win,
    const int* __restrict__ dirs, const int* __restrict__ obs,
    float* __restrict__ partials, int* __restrict__ actArr,
    float* __restrict__ out, int k)
{
  __shared__ float red[4];
  __shared__ float wrl[HH * WRS];
  __shared__ float wot[HH * WOS];
  __shared__ float wint[NDIRS * WRS];
  int t = threadIdx.x;

  float tot = block_reduce_all(partials[t] + partials[t + TPB], red, t);
  int active = (fabsf(tot * INV_BH) > TOLV) ? 1 : 0;
  if (blockIdx.x == 0 && t == 0) actArr[k] = active;

  int si = k & 1;
  int r = blockIdx.x * TPB + t;

  if (!active) {
    int first_inactive = actArr[k - 1];   // written by previous launch (k>=1 here)
    if (!first_inactive) return;          // uniform across grid
    stage_wot(Wout, wot, t, TPB);
    __syncthreads();
    const float* S   = si ? buf1 : buf0;
    const float* scl = si ? scl1 : scl0;
    final_write(r, scl[r], S, out, wot);
    return;
  }

  const float* S    = si ? buf1 : buf0;
  const float* sclS = si ? scl1 : scl0;
  float* W          = si ? buf0 : buf1;
  float* sclW       = si ? scl0 : scl1;
  const float* P    = W;                  // k>=1: prev is the other buffer
  const float* sclP = sclW;

  stage_wr(Wr, wrl, t, TPB);
  stage_wot(Wout, wot, t, TPB);
  stage_wint(Win, wint, t, TPB);
  __syncthreads();

  float a_s = sclS[r];
  float a_p = sclP[r];
  int ob = obs[r];
  int dir = dirs[r];
  const float4* __restrict__ sr4 = (const float4*)(S + (size_t)r * HH);

  float zz[NOB];
  #pragma unroll
  for (int o = 0; o < NOB; ++o) zz[o] = 0.f;
  float sS = 0.f;
  #pragma unroll 1
  for (int h0 = 0; h0 < 16; ++h0) {
    float4 s4 = sr4[h0];
    sS += SUM4(s4);
    const float* t0 = &wot[(h0 * 4 + 0) * WOS];
    const float* t1 = &wot[(h0 * 4 + 1) * WOS];
    const float* t2 = &wot[(h0 * 4 + 2) * WOS];
    const float* t3 = &wot[(h0 * 4 + 3) * WOS];
    #pragma unroll
    for (int o = 0; o < NOB; ++o)
      zz[o] += s4.x * t0[o] + s4.y * t1[o] + s4.z * t2[o] + s4.w * t3[o];
  }

  SOFTJP(zz, a_s, ob)

  __syncthreads();   // live-range firewall: P row enters registers only after phase A

  const float4* __restrict__ pr4 = (const float4*)(P + (size_t)r * HH);
  LOADP(pr4);
  float4* wo4 = (float4*)(W + (size_t)r * HH);
  float ssu = 0.f, su = 0.f;
#define STEP_C_ONE(JJ, COMP) { \
    const float* wr_ = &wrl[(h0 * 4 + JJ) * WRS]; \
    float g_ = fmaxf(fmaf(a_p, DOT64P(wr_), d4.COMP), 0.f); \
    const float* wt_ = &wot[(h0 * 4 + JJ) * WOS]; \
    float w_ = 0.f; \
    _Pragma("unroll") \
    for (int o = 0; o < NOB; ++o) w_ += zz[o] * wt_[o]; \
    float sv_ = a_s * s4.COMP; \
    float uu_ = fmaf(LR_IT, g_ - sv_ + w_, sv_); \
    u.COMP = uu_; ssu += uu_ * uu_; su += uu_; }
  #pragma unroll 1
  for (int h0 = 0; h0 < 16; ++h0) {
    float4 s4 = sr4[h0];
    float4 d4 = *(const float4*)&wint[dir * WRS + h0 * 4];
    float4 u;
    STEP_C_ONE(0, x) STEP_C_ONE(1, y) STEP_C_ONE(2, z) STEP_C_ONE(3, w)
    wo4[h0] = u;
  }
  float inv_u = 1.f / (sqrtf(ssu) + EPSV);
  sclW[r] = inv_u;

  float tot2 = block_reduce_all(a_s * sS - inv_u * su, red, t);
  if (t == 0) partials[blockIdx.x] = tot2;
}

// ---- tail: only fires when all 10 steps were active ----
__global__ __launch_bounds__(TPB, 2) void final_kernel(
    const float* __restrict__ buf0, float* __restrict__ out,
    const float* __restrict__ scl0,
    const float* __restrict__ Wout, const int* __restrict__ actArr)
{
  if (actArr[9] == 0) return;
  __shared__ float wot[HH * WOS];
  int t = threadIdx.x;
  stage_wot(Wout, wot, t, TPB);
  __syncthreads();
  int r = blockIdx.x * TPB + t;   // 10 active steps: s10 in buf0/scl0 (10&1==0)
  final_write(r, scl0[r], buf0, out, wot);
}

extern "C" void kernel_launch(void* const* d_in, const int* in_sizes, int n_in,
                              void* d_out, int out_size, void* d_ws, size_t ws_size,
                              hipStream_t stream) {
  const int* dirs = (const int*)d_in[0];
  const int* obs = (const int*)d_in[1];
  const float* x = (const float*)d_in[2];
  const float* Wr = (const float*)d_in[3];
  const float* Win = (const float*)d_in[4];
  const float* Wout = (const float*)d_in[5];
  float* out = (float*)d_out;
  float* ws = (float*)d_ws;

  float* buf0 = ws;                              // B*H raw state
  float* sclX = ws + (size_t)BB * HH;            // B
  float* scl0 = sclX + BB;                       // B
  float* scl1 = scl0 + BB;                       // B
  float* partials = scl1 + BB;                   // NBLK
  int* actArr = (int*)(partials + NBLK);         // 10 ints
  float* buf1 = out + (size_t)BB * NOB;          // s-slice of d_out doubles as state

  init_kernel<<<NBLK, TPB, 0, stream>>>(x, dirs, Wr, Win, buf0, sclX, scl0, partials);
  step0_kernel<<<NBLK, TPB0, 0, stream>>>(buf0, buf1, scl0, scl1, Wout, obs,
                                          partials, actArr, out);
  for (int k = 1; k < 10; ++k)
    step_kernel<<<NBLK, TPB, 0, stream>>>(x, buf0, buf1, sclX, scl0, scl1,
                                          Wr, Wout, Win, dirs, obs, partials, actArr, out, k);
  final_kernel<<<NBLK, TPB, 0, stream>>>(buf0, out, scl0, Wout, actArr);
}

// Round 10
// 155.923 us; speedup vs baseline: 1.6119x; 1.1092x over previous
//
#include <hip/hip_runtime.h>
#include <math.h>

#define BB 131072
#define HH 64
#define NOB 32
#define NDIRS 8
#define LR_IT 1e-3f
#define TOLV 1e-3f
#define EPSV 1e-6f
#define NBLK 512
#define TPB 256
#define WRS 68   // LDS row stride (floats) for Wr / WinT
#define WOS 36   // LDS row stride for WoutT
#define INV_BH (1.0f/8388608.0f)   // 1/(B*H)

// macro params must not be named x/y/z/w (textual expansion vs .x/.y/.z/.w members)
#define D16(pp, Wp, b) ((pp).x*(Wp)[(b)+0] + (pp).y*(Wp)[(b)+1] + (pp).z*(Wp)[(b)+2] + (pp).w*(Wp)[(b)+3])
#define DOT64P(Wp) (D16(p0,Wp,0)+D16(p1,Wp,4)+D16(p2,Wp,8)+D16(p3,Wp,12)+ \
                    D16(p4,Wp,16)+D16(p5,Wp,20)+D16(p6,Wp,24)+D16(p7,Wp,28)+ \
                    D16(p8,Wp,32)+D16(p9,Wp,36)+D16(p10,Wp,40)+D16(p11,Wp,44)+ \
                    D16(p12,Wp,48)+D16(p13,Wp,52)+D16(p14,Wp,56)+D16(p15,Wp,60))
#define LOADP(src) \
  float4 p0=(src)[0], p1=(src)[1], p2=(src)[2], p3=(src)[3], \
         p4=(src)[4], p5=(src)[5], p6=(src)[6], p7=(src)[7], \
         p8=(src)[8], p9=(src)[9], p10=(src)[10], p11=(src)[11], \
         p12=(src)[12], p13=(src)[13], p14=(src)[14], p15=(src)[15];
#define SUMSQ4(pp) ((pp).x*(pp).x + (pp).y*(pp).y + (pp).z*(pp).z + (pp).w*(pp).w)
#define SUM4(pp) ((pp).x + (pp).y + (pp).z + (pp).w)

// ---- LDS staging (stride = blockDim) ----
__device__ __forceinline__ void stage_wr(const float* __restrict__ Wr, float* wrl, int t, int bs) {
  const float4* g = (const float4*)Wr;           // Wr row-major [64][64]
  for (int i = t; i < 1024; i += bs) {
    int h = i >> 4, k4 = i & 15;
    *(float4*)&wrl[h * WRS + k4 * 4] = g[i];
  }
}
__device__ __forceinline__ void stage_wot(const float* __restrict__ Wout, float* wot, int t, int bs) {
  for (int i = t; i < NOB * HH; i += bs) {       // Wout [32][64] -> wot[h][o]
    int o = i >> 6, h = i & 63;
    wot[h * WOS + o] = Wout[i];
  }
}
__device__ __forceinline__ void stage_wint(const float* __restrict__ Win, float* wint, int t, int bs) {
  for (int i = t; i < HH * NDIRS; i += bs) {     // Win [64][8] -> wint[d][h]
    int h = i >> 3, d = i & 7;
    wint[d * WRS + h] = Win[i];
  }
}

// 256-thread (4-wave) block reduction; returns block total to ALL threads.
// Double-syncthreads internally -> safe back-to-back.
__device__ __forceinline__ float block_reduce_all(float v, float* red, int t) {
  #pragma unroll
  for (int off = 32; off > 0; off >>= 1) v += __shfl_down(v, off);
  __syncthreads();
  if ((t & 63) == 0) red[t >> 6] = v;
  __syncthreads();
  return red[0] + red[1] + red[2] + red[3];
}

// softmax(a_s * zz) -> jacobian-applied jp, in place (zz starts as raw logits)
#define SOFTJP(zzp, a_sv, obv) { \
  float m_ = -1e30f; \
  _Pragma("unroll") for (int o_=0;o_<NOB;++o_) m_ = fmaxf(m_, (zzp)[o_]); \
  float se_ = 0.f; \
  _Pragma("unroll") for (int o_=0;o_<NOB;++o_){ (zzp)[o_]=__expf((a_sv)*((zzp)[o_]-m_)); se_+=(zzp)[o_];} \
  float rse_ = 1.f/se_; float fob_=0.f, sf2_=0.f; \
  _Pragma("unroll") for (int o_=0;o_<NOB;++o_){ float f_=(zzp)[o_]*rse_; (zzp)[o_]=f_; sf2_+=f_*f_; fob_ += (o_==(obv))?f_:0.f;} \
  float fe_ = fob_ - sf2_; \
  _Pragma("unroll") for (int o_=0;o_<NOB;++o_){ float ep_=((o_==(obv))?1.f:0.f)-(zzp)[o_]; (zzp)[o_]=(zzp)[o_]*(ep_-fe_);} }

// preds = softmax(a_s * S_raw @ wot) -> out[:B*32]; a_s*S_raw -> out[B*32:]
__device__ __forceinline__ void final_write(
    int r, float a_s, const float* __restrict__ S, float* __restrict__ out,
    const float* wot) {
  const float4* __restrict__ sr4 = (const float4*)(S + (size_t)r * HH);
  float zz[NOB];
  #pragma unroll
  for (int o = 0; o < NOB; ++o) zz[o] = 0.f;
  #pragma unroll 1
  for (int h0 = 0; h0 < 16; ++h0) {
    float4 s4 = sr4[h0];
    const float* t0 = &wot[(h0 * 4 + 0) * WOS];
    const float* t1 = &wot[(h0 * 4 + 1) * WOS];
    const float* t2 = &wot[(h0 * 4 + 2) * WOS];
    const float* t3 = &wot[(h0 * 4 + 3) * WOS];
    #pragma unroll
    for (int o = 0; o < NOB; ++o)
      zz[o] += s4.x * t0[o] + s4.y * t1[o] + s4.z * t2[o] + s4.w * t3[o];
  }
  float m = -1e30f;
  #pragma unroll
  for (int o = 0; o < NOB; ++o) m = fmaxf(m, zz[o]);
  float se = 0.f;
  #pragma unroll
  for (int o = 0; o < NOB; ++o) { zz[o] = __expf(a_s * (zz[o] - m)); se += zz[o]; }
  float rse = 1.f / se;

  float4* po = (float4*)(out + (size_t)r * NOB);
  #pragma unroll
  for (int o4 = 0; o4 < 8; ++o4) {
    float4 f;
    f.x = zz[o4 * 4 + 0] * rse; f.y = zz[o4 * 4 + 1] * rse;
    f.z = zz[o4 * 4 + 2] * rse; f.w = zz[o4 * 4 + 3] * rse;
    po[o4] = f;
  }
  float4* so = (float4*)(out + (size_t)BB * NOB + (size_t)r * HH);
  #pragma unroll 1
  for (int h0 = 0; h0 < 16; ++h0) {
    float4 s4 = sr4[h0];    // in-place safe: same thread reads then writes same addr
    s4.x *= a_s; s4.y *= a_s; s4.z *= a_s; s4.w *= a_s;
    so[h0] = s4;
  }
}

// ---- fused: init + iteration-0 candidate in ONE pass ----
// s0_raw -> buf0 (+scl0); s1_candidate_raw -> buf1 (+scl1);
// partials0 = per-block sum(prev - s0); partials1 = per-block sum(s0n - s1n).
__global__ __launch_bounds__(TPB, 2) void fused_kernel(
    const float* __restrict__ x, const int* __restrict__ dirs,
    const int* __restrict__ obs,
    const float* __restrict__ Wr, const float* __restrict__ Win,
    const float* __restrict__ Wout,
    float* __restrict__ buf0, float* __restrict__ buf1,
    float* __restrict__ scl0, float* __restrict__ scl1,
    float* __restrict__ partials0, float* __restrict__ partials1)
{
  __shared__ float wrl[HH * WRS];
  __shared__ float wot[HH * WOS];
  __shared__ float wint[NDIRS * WRS];
  __shared__ float red[4];
  int t = threadIdx.x;
  stage_wr(Wr, wrl, t, TPB);
  stage_wot(Wout, wot, t, TPB);
  stage_wint(Win, wint, t, TPB);
  __syncthreads();

  int r = blockIdx.x * TPB + t;
  const float4* __restrict__ xr = (const float4*)(x + (size_t)r * HH);
  LOADP(xr);

  float ssx = SUMSQ4(p0)+SUMSQ4(p1)+SUMSQ4(p2)+SUMSQ4(p3)+SUMSQ4(p4)+SUMSQ4(p5)+
              SUMSQ4(p6)+SUMSQ4(p7)+SUMSQ4(p8)+SUMSQ4(p9)+SUMSQ4(p10)+SUMSQ4(p11)+
              SUMSQ4(p12)+SUMSQ4(p13)+SUMSQ4(p14)+SUMSQ4(p15);
  float sx  = SUM4(p0)+SUM4(p1)+SUM4(p2)+SUM4(p3)+SUM4(p4)+SUM4(p5)+SUM4(p6)+SUM4(p7)+
              SUM4(p8)+SUM4(p9)+SUM4(p10)+SUM4(p11)+SUM4(p12)+SUM4(p13)+SUM4(p14)+SUM4(p15);
  float inv_x = 1.f / (sqrtf(ssx) + EPSV);
  int dir = dirs[r];
  int ob = obs[r];

  // matvec+relu+drive -> s0 raw chunks; phase-A logits accumulated inline
  float zz[NOB];
  #pragma unroll
  for (int o = 0; o < NOB; ++o) zz[o] = 0.f;
  float4* bo = (float4*)(buf0 + (size_t)r * HH);
  float ssg = 0.f, sg = 0.f;
#define INIT_ONE(JJ, COMP) { \
    const float* wr_ = &wrl[(h0 * 4 + JJ) * WRS]; \
    u.COMP = fmaxf(fmaf(inv_x, DOT64P(wr_), d4.COMP), 0.f); }
  #pragma unroll 1
  for (int h0 = 0; h0 < 16; ++h0) {
    float4 d4 = *(const float4*)&wint[dir * WRS + h0 * 4];
    float4 u;
    INIT_ONE(0, x) INIT_ONE(1, y) INIT_ONE(2, z) INIT_ONE(3, w)
    bo[h0] = u;
    ssg += SUMSQ4(u); sg += SUM4(u);
    const float* t0 = &wot[(h0 * 4 + 0) * WOS];
    const float* t1 = &wot[(h0 * 4 + 1) * WOS];
    const float* t2 = &wot[(h0 * 4 + 2) * WOS];
    const float* t3 = &wot[(h0 * 4 + 3) * WOS];
    #pragma unroll
    for (int o = 0; o < NOB; ++o)
      zz[o] += u.x * t0[o] + u.y * t1[o] + u.z * t2[o] + u.w * t3[o];
  }
  float inv_g = 1.f / (sqrtf(ssg) + EPSV);
  scl0[r] = inv_g;
  float a_s = inv_g;

  SOFTJP(zz, a_s, ob)

  // phase C: re-read s0 row (L1/L2-hot, just written by this thread)
  // g = relu(prev@Wr+drive) == raw s0 at iteration 0; s = a_s * s0_raw
  const float4* __restrict__ sr4 = (const float4*)(buf0 + (size_t)r * HH);
  float4* wo4 = (float4*)(buf1 + (size_t)r * HH);
  float ssu = 0.f, su = 0.f;
#define F0_ONE(JJ, COMP) { \
    const float* wt_ = &wot[(h0 * 4 + JJ) * WOS]; \
    float w_ = 0.f; \
    _Pragma("unroll") \
    for (int o = 0; o < NOB; ++o) w_ += zz[o] * wt_[o]; \
    float g_ = g4.COMP; \
    float sv_ = a_s * g_; \
    float uu_ = fmaf(LR_IT, g_ - sv_ + w_, sv_); \
    u.COMP = uu_; ssu += uu_ * uu_; su += uu_; }
  #pragma unroll 1
  for (int h0 = 0; h0 < 16; ++h0) {
    float4 g4 = sr4[h0];
    float4 u;
    F0_ONE(0, x) F0_ONE(1, y) F0_ONE(2, z) F0_ONE(3, w)
    wo4[h0] = u;
  }
  float inv_u = 1.f / (sqrtf(ssu) + EPSV);
  scl1[r] = inv_u;

  float tot0 = block_reduce_all(inv_x * sx - inv_g * sg, red, t);
  if (t == 0) partials0[blockIdx.x] = tot0;
  float tot1 = block_reduce_all(a_s * sg - inv_u * su, red, t);  // sum(s0n) - sum(s1n)
  if (t == 0) partials1[blockIdx.x] = tot1;
}

// ---- resolve: decide act0/act1 (grid-uniform), expected path writes output ----
__global__ __launch_bounds__(TPB, 2) void resolve_kernel(
    float* __restrict__ buf0, float* __restrict__ buf1,
    float* __restrict__ scl0, float* __restrict__ scl1,
    const float* __restrict__ Wr, const float* __restrict__ Wout,
    const float* __restrict__ Win,
    const int* __restrict__ dirs, const int* __restrict__ obs,
    const float* __restrict__ partials0, float* __restrict__ partials,
    int* __restrict__ actArr, float* __restrict__ out)
{
  __shared__ float wrl[HH * WRS];
  __shared__ float wot[HH * WOS];
  __shared__ float wint[NDIRS * WRS];
  __shared__ float red[4];
  int t = threadIdx.x;

  float t0v = block_reduce_all(partials0[t] + partials0[t + TPB], red, t);
  int act0 = (fabsf(t0v * INV_BH) > TOLV) ? 1 : 0;
  float t1v = block_reduce_all(partials[t] + partials[t + TPB], red, t);
  int act1 = (fabsf(t1v * INV_BH) > TOLV) ? 1 : 0;
  if (blockIdx.x == 0 && t == 0) actArr[1] = act0 && act1;

  int r = blockIdx.x * TPB + t;

  if (!act0) {
    // iteration 0 inactive: final = s0. Keep sticky invariant: partials <= tol.
    if (t == 0) partials[blockIdx.x] = partials0[blockIdx.x];
    stage_wot(Wout, wot, t, TPB);
    __syncthreads();
    final_write(r, scl0[r], buf0, out, wot);
    return;
  }
  if (!act1) {
    // expected path: iteration 1 inactive: final = s1 (buf1 is the out s-slice).
    stage_wot(Wout, wot, t, TPB);
    __syncthreads();
    final_write(r, scl1[r], buf1, out, wot);
    return;
  }

  // both active: run iteration 1 fully. S=buf1/scl1, P=buf0 (norm scl0), W=buf0/scl0.
  stage_wr(Wr, wrl, t, TPB);
  stage_wot(Wout, wot, t, TPB);
  stage_wint(Win, wint, t, TPB);
  __syncthreads();

  float a_s = scl1[r];
  float a_p = scl0[r];
  int ob = obs[r];
  int dir = dirs[r];
  const float4* __restrict__ sr4 = (const float4*)(buf1 + (size_t)r * HH);

  float zz[NOB];
  #pragma unroll
  for (int o = 0; o < NOB; ++o) zz[o] = 0.f;
  float sS = 0.f;
  #pragma unroll 1
  for (int h0 = 0; h0 < 16; ++h0) {
    float4 s4 = sr4[h0];
    sS += SUM4(s4);
    const float* t0 = &wot[(h0 * 4 + 0) * WOS];
    const float* t1 = &wot[(h0 * 4 + 1) * WOS];
    const float* t2 = &wot[(h0 * 4 + 2) * WOS];
    const float* t3 = &wot[(h0 * 4 + 3) * WOS];
    #pragma unroll
    for (int o = 0; o < NOB; ++o)
      zz[o] += s4.x * t0[o] + s4.y * t1[o] + s4.z * t2[o] + s4.w * t3[o];
  }
  SOFTJP(zz, a_s, ob)
  __syncthreads();   // live-range firewall

  const float4* __restrict__ pr4 = (const float4*)(buf0 + (size_t)r * HH);
  LOADP(pr4);
  float4* wo4 = (float4*)(buf0 + (size_t)r * HH);
  float ssu = 0.f, su = 0.f;
#define STEP_C_ONE(JJ, COMP) { \
    const float* wr_ = &wrl[(h0 * 4 + JJ) * WRS]; \
    float g_ = fmaxf(fmaf(a_p, DOT64P(wr_), d4.COMP), 0.f); \
    const float* wt_ = &wot[(h0 * 4 + JJ) * WOS]; \
    float w_ = 0.f; \
    _Pragma("unroll") \
    for (int o = 0; o < NOB; ++o) w_ += zz[o] * wt_[o]; \
    float sv_ = a_s * s4.COMP; \
    float uu_ = fmaf(LR_IT, g_ - sv_ + w_, sv_); \
    u.COMP = uu_; ssu += uu_ * uu_; su += uu_; }
  #pragma unroll 1
  for (int h0 = 0; h0 < 16; ++h0) {
    float4 s4 = sr4[h0];
    float4 d4 = *(const float4*)&wint[dir * WRS + h0 * 4];
    float4 u;
    STEP_C_ONE(0, x) STEP_C_ONE(1, y) STEP_C_ONE(2, z) STEP_C_ONE(3, w)
    wo4[h0] = u;
  }
  float inv_u = 1.f / (sqrtf(ssu) + EPSV);
  scl0[r] = inv_u;

  float tot2 = block_reduce_all(a_s * sS - inv_u * su, red, t);
  if (t == 0) partials[blockIdx.x] = tot2;
}

// ---- generic step k>=2: gate + (active | first-inactive final | no-op) ----
__global__ __launch_bounds__(TPB, 2) void step_kernel(
    float* __restrict__ buf0, float* __restrict__ buf1,
    float* __restrict__ scl0, float* __restrict__ scl1,
    const float* __restrict__ Wr, const float* __restrict__ Wout,
    const float* __restrict__ Win,
    const int* __restrict__ dirs, const int* __restrict__ obs,
    float* __restrict__ partials, int* __restrict__ actArr,
    float* __restrict__ out, int k)
{
  __shared__ float red[4];
  __shared__ float wrl[HH * WRS];
  __shared__ float wot[HH * WOS];
  __shared__ float wint[NDIRS * WRS];
  int t = threadIdx.x;

  float tot = block_reduce_all(partials[t] + partials[t + TPB], red, t);
  int active = (fabsf(tot * INV_BH) > TOLV) ? 1 : 0;
  if (blockIdx.x == 0 && t == 0) actArr[k] = active;

  int si = k & 1;
  int r = blockIdx.x * TPB + t;

  if (!active) {
    int first_inactive = actArr[k - 1];   // written by previous launch
    if (!first_inactive) return;          // uniform across grid
    stage_wot(Wout, wot, t, TPB);
    __syncthreads();
    const float* S   = si ? buf1 : buf0;
    const float* scl = si ? scl1 : scl0;
    final_write(r, scl[r], S, out, wot);
    return;
  }

  const float* S    = si ? buf1 : buf0;
  const float* sclS = si ? scl1 : scl0;
  float* W          = si ? buf0 : buf1;
  float* sclW       = si ? scl0 : scl1;

  stage_wr(Wr, wrl, t, TPB);
  stage_wot(Wout, wot, t, TPB);
  stage_wint(Win, wint, t, TPB);
  __syncthreads();

  float a_s = sclS[r];
  float a_p = sclW[r];
  int ob = obs[r];
  int dir = dirs[r];
  const float4* __restrict__ sr4 = (const float4*)(S + (size_t)r * HH);

  float zz[NOB];
  #pragma unroll
  for (int o = 0; o < NOB; ++o) zz[o] = 0.f;
  float sS = 0.f;
  #pragma unroll 1
  for (int h0 = 0; h0 < 16; ++h0) {
    float4 s4 = sr4[h0];
    sS += SUM4(s4);
    const float* t0 = &wot[(h0 * 4 + 0) * WOS];
    const float* t1 = &wot[(h0 * 4 + 1) * WOS];
    const float* t2 = &wot[(h0 * 4 + 2) * WOS];
    const float* t3 = &wot[(h0 * 4 + 3) * WOS];
    #pragma unroll
    for (int o = 0; o < NOB; ++o)
      zz[o] += s4.x * t0[o] + s4.y * t1[o] + s4.z * t2[o] + s4.w * t3[o];
  }
  SOFTJP(zz, a_s, ob)
  __syncthreads();   // live-range firewall

  const float4* __restrict__ pr4 = (const float4*)(W + (size_t)r * HH);
  LOADP(pr4);
  float4* wo4 = (float4*)(W + (size_t)r * HH);
  float ssu = 0.f, su = 0.f;
  #pragma unroll 1
  for (int h0 = 0; h0 < 16; ++h0) {
    float4 s4 = sr4[h0];
    float4 d4 = *(const float4*)&wint[dir * WRS + h0 * 4];
    float4 u;
    STEP_C_ONE(0, x) STEP_C_ONE(1, y) STEP_C_ONE(2, z) STEP_C_ONE(3, w)
    wo4[h0] = u;
  }
  float inv_u = 1.f / (sqrtf(ssu) + EPSV);
  sclW[r] = inv_u;

  float tot2 = block_reduce_all(a_s * sS - inv_u * su, red, t);
  if (t == 0) partials[blockIdx.x] = tot2;
}

// ---- tail: only fires when all 10 iterations were active ----
__global__ __launch_bounds__(TPB, 2) void final_kernel(
    const float* __restrict__ buf0, float* __restrict__ out,
    const float* __restrict__ scl0,
    const float* __restrict__ Wout, const int* __restrict__ actArr)
{
  if (actArr[9] == 0) return;
  __shared__ float wot[HH * WOS];
  int t = threadIdx.x;
  stage_wot(Wout, wot, t, TPB);
  __syncthreads();
  int r = blockIdx.x * TPB + t;   // 10 active iterations: s10 in buf0/scl0
  final_write(r, scl0[r], buf0, out, wot);
}

extern "C" void kernel_launch(void* const* d_in, const int* in_sizes, int n_in,
                              void* d_out, int out_size, void* d_ws, size_t ws_size,
                              hipStream_t stream) {
  const int* dirs = (const int*)d_in[0];
  const int* obs = (const int*)d_in[1];
  const float* x = (const float*)d_in[2];
  const float* Wr = (const float*)d_in[3];
  const float* Win = (const float*)d_in[4];
  const float* Wout = (const float*)d_in[5];
  float* out = (float*)d_out;
  float* ws = (float*)d_ws;

  float* buf0 = ws;                              // B*H raw state s0 (then s2,s4,..)
  float* scl0 = ws + (size_t)BB * HH;            // B
  float* scl1 = scl0 + BB;                       // B
  float* partials = scl1 + BB;                   // NBLK (gate for "current" iteration)
  float* partials0 = partials + NBLK;            // NBLK (gate0)
  int* actArr = (int*)(partials0 + NBLK);        // 16 ints
  float* buf1 = out + (size_t)BB * NOB;          // s-slice of d_out: s1 (then s3,..)

  fused_kernel<<<NBLK, TPB, 0, stream>>>(x, dirs, obs, Wr, Win, Wout,
                                         buf0, buf1, scl0, scl1, partials0, partials);
  resolve_kernel<<<NBLK, TPB, 0, stream>>>(buf0, buf1, scl0, scl1, Wr, Wout, Win,
                                           dirs, obs, partials0, partials, actArr, out);
  for (int k = 2; k < 10; ++k)
    step_kernel<<<NBLK, TPB, 0, stream>>>(buf0, buf1, scl0, scl1,
                                          Wr, Wout, Win, dirs, obs, partials, actArr, out, k);
  final_kernel<<<NBLK, TPB, 0, stream>>>(buf0, out, scl0, Wout, actArr);
}

// Round 11
// 149.547 us; speedup vs baseline: 1.6807x; 1.0426x over previous
//
#include <hip/hip_runtime.h>
#include <math.h>

#define BB 131072
#define HH 64
#define NOB 32
#define NDIRS 8
#define LR_IT 1e-3f
#define TOLV 1e-3f
#define EPSV 1e-6f
#define NBLK 512
#define TPB 256
#define WRS 68   // LDS row stride (floats) for Wr / WinT
#define WOS 36   // LDS row stride for WoutT
#define INV_BH (1.0f/8388608.0f)   // 1/(B*H)

// macro params must not be named x/y/z/w (textual expansion vs .x/.y/.z/.w members)
#define D16(pp, Wp, b) ((pp).x*(Wp)[(b)+0] + (pp).y*(Wp)[(b)+1] + (pp).z*(Wp)[(b)+2] + (pp).w*(Wp)[(b)+3])
#define DOT64P(Wp) (D16(p0,Wp,0)+D16(p1,Wp,4)+D16(p2,Wp,8)+D16(p3,Wp,12)+ \
                    D16(p4,Wp,16)+D16(p5,Wp,20)+D16(p6,Wp,24)+D16(p7,Wp,28)+ \
                    D16(p8,Wp,32)+D16(p9,Wp,36)+D16(p10,Wp,40)+D16(p11,Wp,44)+ \
                    D16(p12,Wp,48)+D16(p13,Wp,52)+D16(p14,Wp,56)+D16(p15,Wp,60))
#define LOADP(src) \
  float4 p0=(src)[0], p1=(src)[1], p2=(src)[2], p3=(src)[3], \
         p4=(src)[4], p5=(src)[5], p6=(src)[6], p7=(src)[7], \
         p8=(src)[8], p9=(src)[9], p10=(src)[10], p11=(src)[11], \
         p12=(src)[12], p13=(src)[13], p14=(src)[14], p15=(src)[15];
#define SUMSQ4(pp) ((pp).x*(pp).x + (pp).y*(pp).y + (pp).z*(pp).z + (pp).w*(pp).w)
#define SUM4(pp) ((pp).x + (pp).y + (pp).z + (pp).w)

// ---- LDS staging (stride = blockDim) ----
__device__ __forceinline__ void stage_wr(const float* __restrict__ Wr, float* wrl, int t, int bs) {
  const float4* g = (const float4*)Wr;           // Wr row-major [64][64]
  for (int i = t; i < 1024; i += bs) {
    int h = i >> 4, k4 = i & 15;
    *(float4*)&wrl[h * WRS + k4 * 4] = g[i];
  }
}
__device__ __forceinline__ void stage_wot(const float* __restrict__ Wout, float* wot, int t, int bs) {
  for (int i = t; i < NOB * HH; i += bs) {       // Wout [32][64] -> wot[h][o]
    int o = i >> 6, h = i & 63;
    wot[h * WOS + o] = Wout[i];
  }
}
__device__ __forceinline__ void stage_wint(const float* __restrict__ Win, float* wint, int t, int bs) {
  for (int i = t; i < HH * NDIRS; i += bs) {     // Win [64][8] -> wint[d][h]
    int h = i >> 3, d = i & 7;
    wint[d * WRS + h] = Win[i];
  }
}

// 256-thread (4-wave) block reduction; returns block total to ALL threads.
// Double-syncthreads internally -> safe back-to-back.
__device__ __forceinline__ float block_reduce_all(float v, float* red, int t) {
  #pragma unroll
  for (int off = 32; off > 0; off >>= 1) v += __shfl_down(v, off);
  __syncthreads();
  if ((t & 63) == 0) red[t >> 6] = v;
  __syncthreads();
  return red[0] + red[1] + red[2] + red[3];
}

// softmax(a_s * zz) -> jacobian-applied jp, in place (zz starts as raw logits)
#define SOFTJP(zzp, a_sv, obv) { \
  float m_ = -1e30f; \
  _Pragma("unroll") for (int o_=0;o_<NOB;++o_) m_ = fmaxf(m_, (zzp)[o_]); \
  float se_ = 0.f; \
  _Pragma("unroll") for (int o_=0;o_<NOB;++o_){ (zzp)[o_]=__expf((a_sv)*((zzp)[o_]-m_)); se_+=(zzp)[o_];} \
  float rse_ = 1.f/se_; float fob_=0.f, sf2_=0.f; \
  _Pragma("unroll") for (int o_=0;o_<NOB;++o_){ float f_=(zzp)[o_]*rse_; (zzp)[o_]=f_; sf2_+=f_*f_; fob_ += (o_==(obv))?f_:0.f;} \
  float fe_ = fob_ - sf2_; \
  _Pragma("unroll") for (int o_=0;o_<NOB;++o_){ float ep_=((o_==(obv))?1.f:0.f)-(zzp)[o_]; (zzp)[o_]=(zzp)[o_]*(ep_-fe_);} }

// preds = softmax(a_s * S_raw @ wot) -> out[:B*32]; a_s*S_raw -> out[B*32:]
__device__ __forceinline__ void final_write(
    int r, float a_s, const float* __restrict__ S, float* __restrict__ out,
    const float* wot) {
  const float4* __restrict__ sr4 = (const float4*)(S + (size_t)r * HH);
  float zz[NOB];
  #pragma unroll
  for (int o = 0; o < NOB; ++o) zz[o] = 0.f;
  #pragma unroll 1
  for (int h0 = 0; h0 < 16; ++h0) {
    float4 s4 = sr4[h0];
    const float* t0 = &wot[(h0 * 4 + 0) * WOS];
    const float* t1 = &wot[(h0 * 4 + 1) * WOS];
    const float* t2 = &wot[(h0 * 4 + 2) * WOS];
    const float* t3 = &wot[(h0 * 4 + 3) * WOS];
    #pragma unroll
    for (int o = 0; o < NOB; ++o)
      zz[o] += s4.x * t0[o] + s4.y * t1[o] + s4.z * t2[o] + s4.w * t3[o];
  }
  float m = -1e30f;
  #pragma unroll
  for (int o = 0; o < NOB; ++o) m = fmaxf(m, zz[o]);
  float se = 0.f;
  #pragma unroll
  for (int o = 0; o < NOB; ++o) { zz[o] = __expf(a_s * (zz[o] - m)); se += zz[o]; }
  float rse = 1.f / se;

  float4* po = (float4*)(out + (size_t)r * NOB);
  #pragma unroll
  for (int o4 = 0; o4 < 8; ++o4) {
    float4 f;
    f.x = zz[o4 * 4 + 0] * rse; f.y = zz[o4 * 4 + 1] * rse;
    f.z = zz[o4 * 4 + 2] * rse; f.w = zz[o4 * 4 + 3] * rse;
    po[o4] = f;
  }
  float4* so = (float4*)(out + (size_t)BB * NOB + (size_t)r * HH);
  #pragma unroll 1
  for (int h0 = 0; h0 < 16; ++h0) {
    float4 s4 = sr4[h0];    // in-place safe: same thread reads then writes same addr
    s4.x *= a_s; s4.y *= a_s; s4.z *= a_s; s4.w *= a_s;
    so[h0] = s4;
  }
}

// ---- fused: init + iteration-0 candidate, two passes with a live-range firewall ----
// Pass 1 (x live): s0_raw -> buf0 (+scl0).  Firewall.  Pass 2 (zz live): logits
// from the L1-hot buf0 row, softmax/jp, s1_candidate -> buf1 (+scl1).
// partials0 = per-block sum(prev - s0); partials1 = per-block sum(s0n - s1n).
__global__ __launch_bounds__(TPB, 2) void fused_kernel(
    const float* __restrict__ x, const int* __restrict__ dirs,
    const int* __restrict__ obs,
    const float* __restrict__ Wr, const float* __restrict__ Win,
    const float* __restrict__ Wout,
    float* __restrict__ buf0, float* __restrict__ buf1,
    float* __restrict__ scl0, float* __restrict__ scl1,
    float* __restrict__ partials0, float* __restrict__ partials1)
{
  __shared__ float wrl[HH * WRS];
  __shared__ float wot[HH * WOS];
  __shared__ float wint[NDIRS * WRS];
  __shared__ float red[4];
  int t = threadIdx.x;
  stage_wr(Wr, wrl, t, TPB);
  stage_wot(Wout, wot, t, TPB);
  stage_wint(Win, wint, t, TPB);
  __syncthreads();

  int r = blockIdx.x * TPB + t;
  float gate0, a_s, sg;

  // ---- pass 1: x row in registers; s0 = relu(inv_x * x@WrT + drive) ----
  {
    const float4* __restrict__ xr = (const float4*)(x + (size_t)r * HH);
    LOADP(xr);
    float ssx = SUMSQ4(p0)+SUMSQ4(p1)+SUMSQ4(p2)+SUMSQ4(p3)+SUMSQ4(p4)+SUMSQ4(p5)+
                SUMSQ4(p6)+SUMSQ4(p7)+SUMSQ4(p8)+SUMSQ4(p9)+SUMSQ4(p10)+SUMSQ4(p11)+
                SUMSQ4(p12)+SUMSQ4(p13)+SUMSQ4(p14)+SUMSQ4(p15);
    float sx  = SUM4(p0)+SUM4(p1)+SUM4(p2)+SUM4(p3)+SUM4(p4)+SUM4(p5)+SUM4(p6)+SUM4(p7)+
                SUM4(p8)+SUM4(p9)+SUM4(p10)+SUM4(p11)+SUM4(p12)+SUM4(p13)+SUM4(p14)+SUM4(p15);
    float inv_x = 1.f / (sqrtf(ssx) + EPSV);
    int dir = dirs[r];

    float4* bo = (float4*)(buf0 + (size_t)r * HH);
    float ssg = 0.f, sgl = 0.f;
#define INIT_ONE(JJ, COMP) { \
      const float* wr_ = &wrl[(h0 * 4 + JJ) * WRS]; \
      u.COMP = fmaxf(fmaf(inv_x, DOT64P(wr_), d4.COMP), 0.f); }
    #pragma unroll 1
    for (int h0 = 0; h0 < 16; ++h0) {
      float4 d4 = *(const float4*)&wint[dir * WRS + h0 * 4];
      float4 u;
      INIT_ONE(0, x) INIT_ONE(1, y) INIT_ONE(2, z) INIT_ONE(3, w)
      bo[h0] = u;
      ssg += SUMSQ4(u); sgl += SUM4(u);
    }
    float inv_g = 1.f / (sqrtf(ssg) + EPSV);
    scl0[r] = inv_g;
    a_s = inv_g;
    sg = sgl;
    gate0 = inv_x * sx - inv_g * sgl;
  }

  __syncthreads();   // live-range firewall: x row dies here

  // ---- pass 2: logits from the hot buf0 row; softmax/jp; phase C ----
  int ob = obs[r];
  const float4* __restrict__ sr4 = (const float4*)(buf0 + (size_t)r * HH);
  float zz[NOB];
  #pragma unroll
  for (int o = 0; o < NOB; ++o) zz[o] = 0.f;
  #pragma unroll 1
  for (int h0 = 0; h0 < 16; ++h0) {
    float4 s4 = sr4[h0];
    const float* t0 = &wot[(h0 * 4 + 0) * WOS];
    const float* t1 = &wot[(h0 * 4 + 1) * WOS];
    const float* t2 = &wot[(h0 * 4 + 2) * WOS];
    const float* t3 = &wot[(h0 * 4 + 3) * WOS];
    #pragma unroll
    for (int o = 0; o < NOB; ++o)
      zz[o] += s4.x * t0[o] + s4.y * t1[o] + s4.z * t2[o] + s4.w * t3[o];
  }

  SOFTJP(zz, a_s, ob)

  // phase C: g = relu(prev@Wr+drive) == raw s0 at iteration 0; s = a_s * s0_raw
  float4* wo4 = (float4*)(buf1 + (size_t)r * HH);
  float ssu = 0.f, su = 0.f;
#define F0_ONE(JJ, COMP) { \
    const float* wt_ = &wot[(h0 * 4 + JJ) * WOS]; \
    float w_ = 0.f; \
    _Pragma("unroll") \
    for (int o = 0; o < NOB; ++o) w_ += zz[o] * wt_[o]; \
    float g_ = g4.COMP; \
    float sv_ = a_s * g_; \
    float uu_ = fmaf(LR_IT, g_ - sv_ + w_, sv_); \
    u.COMP = uu_; ssu += uu_ * uu_; su += uu_; }
  #pragma unroll 1
  for (int h0 = 0; h0 < 16; ++h0) {
    float4 g4 = sr4[h0];
    float4 u;
    F0_ONE(0, x) F0_ONE(1, y) F0_ONE(2, z) F0_ONE(3, w)
    wo4[h0] = u;
  }
  float inv_u = 1.f / (sqrtf(ssu) + EPSV);
  scl1[r] = inv_u;

  float tot0 = block_reduce_all(gate0, red, t);
  if (t == 0) partials0[blockIdx.x] = tot0;
  float tot1 = block_reduce_all(a_s * sg - inv_u * su, red, t);  // sum(s0n) - sum(s1n)
  if (t == 0) partials1[blockIdx.x] = tot1;
}

// ---- resolve: decide act0/act1 (grid-uniform), expected path writes output ----
__global__ __launch_bounds__(TPB, 2) void resolve_kernel(
    float* __restrict__ buf0, float* __restrict__ buf1,
    float* __restrict__ scl0, float* __restrict__ scl1,
    const float* __restrict__ Wr, const float* __restrict__ Wout,
    const float* __restrict__ Win,
    const int* __restrict__ dirs, const int* __restrict__ obs,
    const float* __restrict__ partials0, float* __restrict__ partials,
    int* __restrict__ actArr, float* __restrict__ out)
{
  __shared__ float wrl[HH * WRS];
  __shared__ float wot[HH * WOS];
  __shared__ float wint[NDIRS * WRS];
  __shared__ float red[4];
  int t = threadIdx.x;

  float t0v = block_reduce_all(partials0[t] + partials0[t + TPB], red, t);
  int act0 = (fabsf(t0v * INV_BH) > TOLV) ? 1 : 0;
  float t1v = block_reduce_all(partials[t] + partials[t + TPB], red, t);
  int act1 = (fabsf(t1v * INV_BH) > TOLV) ? 1 : 0;
  if (blockIdx.x == 0 && t == 0) actArr[1] = act0 && act1;

  int r = blockIdx.x * TPB + t;

  if (!act0) {
    // iteration 0 inactive: final = s0. Keep sticky invariant: partials <= tol.
    if (t == 0) partials[blockIdx.x] = partials0[blockIdx.x];
    stage_wot(Wout, wot, t, TPB);
    __syncthreads();
    final_write(r, scl0[r], buf0, out, wot);
    return;
  }
  if (!act1) {
    // expected path: iteration 1 inactive: final = s1 (buf1 is the out s-slice).
    stage_wot(Wout, wot, t, TPB);
    __syncthreads();
    final_write(r, scl1[r], buf1, out, wot);
    return;
  }

  // both active: run iteration 1 fully. S=buf1/scl1, P=buf0 (norm scl0), W=buf0/scl0.
  stage_wr(Wr, wrl, t, TPB);
  stage_wot(Wout, wot, t, TPB);
  stage_wint(Win, wint, t, TPB);
  __syncthreads();

  float a_s = scl1[r];
  float a_p = scl0[r];
  int ob = obs[r];
  int dir = dirs[r];
  const float4* __restrict__ sr4 = (const float4*)(buf1 + (size_t)r * HH);

  float zz[NOB];
  #pragma unroll
  for (int o = 0; o < NOB; ++o) zz[o] = 0.f;
  float sS = 0.f;
  #pragma unroll 1
  for (int h0 = 0; h0 < 16; ++h0) {
    float4 s4 = sr4[h0];
    sS += SUM4(s4);
    const float* t0 = &wot[(h0 * 4 + 0) * WOS];
    const float* t1 = &wot[(h0 * 4 + 1) * WOS];
    const float* t2 = &wot[(h0 * 4 + 2) * WOS];
    const float* t3 = &wot[(h0 * 4 + 3) * WOS];
    #pragma unroll
    for (int o = 0; o < NOB; ++o)
      zz[o] += s4.x * t0[o] + s4.y * t1[o] + s4.z * t2[o] + s4.w * t3[o];
  }
  SOFTJP(zz, a_s, ob)
  __syncthreads();   // live-range firewall

  const float4* __restrict__ pr4 = (const float4*)(buf0 + (size_t)r * HH);
  LOADP(pr4);
  float4* wo4 = (float4*)(buf0 + (size_t)r * HH);
  float ssu = 0.f, su = 0.f;
#define STEP_C_ONE(JJ, COMP) { \
    const float* wr_ = &wrl[(h0 * 4 + JJ) * WRS]; \
    float g_ = fmaxf(fmaf(a_p, DOT64P(wr_), d4.COMP), 0.f); \
    const float* wt_ = &wot[(h0 * 4 + JJ) * WOS]; \
    float w_ = 0.f; \
    _Pragma("unroll") \
    for (int o = 0; o < NOB; ++o) w_ += zz[o] * wt_[o]; \
    float sv_ = a_s * s4.COMP; \
    float uu_ = fmaf(LR_IT, g_ - sv_ + w_, sv_); \
    u.COMP = uu_; ssu += uu_ * uu_; su += uu_; }
  #pragma unroll 1
  for (int h0 = 0; h0 < 16; ++h0) {
    float4 s4 = sr4[h0];
    float4 d4 = *(const float4*)&wint[dir * WRS + h0 * 4];
    float4 u;
    STEP_C_ONE(0, x) STEP_C_ONE(1, y) STEP_C_ONE(2, z) STEP_C_ONE(3, w)
    wo4[h0] = u;
  }
  float inv_u = 1.f / (sqrtf(ssu) + EPSV);
  scl0[r] = inv_u;

  float tot2 = block_reduce_all(a_s * sS - inv_u * su, red, t);
  if (t == 0) partials[blockIdx.x] = tot2;
}

// ---- generic step k>=2: gate + (active | first-inactive final | no-op) ----
__global__ __launch_bounds__(TPB, 2) void step_kernel(
    float* __restrict__ buf0, float* __restrict__ buf1,
    float* __restrict__ scl0, float* __restrict__ scl1,
    const float* __restrict__ Wr, const float* __restrict__ Wout,
    const float* __restrict__ Win,
    const int* __restrict__ dirs, const int* __restrict__ obs,
    float* __restrict__ partials, int* __restrict__ actArr,
    float* __restrict__ out, int k)
{
  __shared__ float red[4];
  __shared__ float wrl[HH * WRS];
  __shared__ float wot[HH * WOS];
  __shared__ float wint[NDIRS * WRS];
  int t = threadIdx.x;

  float tot = block_reduce_all(partials[t] + partials[t + TPB], red, t);
  int active = (fabsf(tot * INV_BH) > TOLV) ? 1 : 0;
  if (blockIdx.x == 0 && t == 0) actArr[k] = active;

  int si = k & 1;
  int r = blockIdx.x * TPB + t;

  if (!active) {
    int first_inactive = actArr[k - 1];   // written by previous launch
    if (!first_inactive) return;          // uniform across grid
    stage_wot(Wout, wot, t, TPB);
    __syncthreads();
    const float* S   = si ? buf1 : buf0;
    const float* scl = si ? scl1 : scl0;
    final_write(r, scl[r], S, out, wot);
    return;
  }

  const float* S    = si ? buf1 : buf0;
  const float* sclS = si ? scl1 : scl0;
  float* W          = si ? buf0 : buf1;
  float* sclW       = si ? scl0 : scl1;

  stage_wr(Wr, wrl, t, TPB);
  stage_wot(Wout, wot, t, TPB);
  stage_wint(Win, wint, t, TPB);
  __syncthreads();

  float a_s = sclS[r];
  float a_p = sclW[r];
  int ob = obs[r];
  int dir = dirs[r];
  const float4* __restrict__ sr4 = (const float4*)(S + (size_t)r * HH);

  float zz[NOB];
  #pragma unroll
  for (int o = 0; o < NOB; ++o) zz[o] = 0.f;
  float sS = 0.f;
  #pragma unroll 1
  for (int h0 = 0; h0 < 16; ++h0) {
    float4 s4 = sr4[h0];
    sS += SUM4(s4);
    const float* t0 = &wot[(h0 * 4 + 0) * WOS];
    const float* t1 = &wot[(h0 * 4 + 1) * WOS];
    const float* t2 = &wot[(h0 * 4 + 2) * WOS];
    const float* t3 = &wot[(h0 * 4 + 3) * WOS];
    #pragma unroll
    for (int o = 0; o < NOB; ++o)
      zz[o] += s4.x * t0[o] + s4.y * t1[o] + s4.z * t2[o] + s4.w * t3[o];
  }
  SOFTJP(zz, a_s, ob)
  __syncthreads();   // live-range firewall

  const float4* __restrict__ pr4 = (const float4*)(W + (size_t)r * HH);
  LOADP(pr4);
  float4* wo4 = (float4*)(W + (size_t)r * HH);
  float ssu = 0.f, su = 0.f;
  #pragma unroll 1
  for (int h0 = 0; h0 < 16; ++h0) {
    float4 s4 = sr4[h0];
    float4 d4 = *(const float4*)&wint[dir * WRS + h0 * 4];
    float4 u;
    STEP_C_ONE(0, x) STEP_C_ONE(1, y) STEP_C_ONE(2, z) STEP_C_ONE(3, w)
    wo4[h0] = u;
  }
  float inv_u = 1.f / (sqrtf(ssu) + EPSV);
  sclW[r] = inv_u;

  float tot2 = block_reduce_all(a_s * sS - inv_u * su, red, t);
  if (t == 0) partials[blockIdx.x] = tot2;
}

// ---- tail: only fires when all 10 iterations were active ----
__global__ __launch_bounds__(TPB, 2) void final_kernel(
    const float* __restrict__ buf0, float* __restrict__ out,
    const float* __restrict__ scl0,
    const float* __restrict__ Wout, const int* __restrict__ actArr)
{
  if (actArr[9] == 0) return;
  __shared__ float wot[HH * WOS];
  int t = threadIdx.x;
  stage_wot(Wout, wot, t, TPB);
  __syncthreads();
  int r = blockIdx.x * TPB + t;   // 10 active iterations: s10 in buf0/scl0
  final_write(r, scl0[r], buf0, out, wot);
}

extern "C" void kernel_launch(void* const* d_in, const int* in_sizes, int n_in,
                              void* d_out, int out_size, void* d_ws, size_t ws_size,
                              hipStream_t stream) {
  const int* dirs = (const int*)d_in[0];
  const int* obs = (const int*)d_in[1];
  const float* x = (const float*)d_in[2];
  const float* Wr = (const float*)d_in[3];
  const float* Win = (const float*)d_in[4];
  const float* Wout = (const float*)d_in[5];
  float* out = (float*)d_out;
  float* ws = (float*)d_ws;

  float* buf0 = ws;                              // B*H raw state s0 (then s2,s4,..)
  float* scl0 = ws + (size_t)BB * HH;            // B
  float* scl1 = scl0 + BB;                       // B
  float* partials = scl1 + BB;                   // NBLK (gate for "current" iteration)
  float* partials0 = partials + NBLK;            // NBLK (gate0)
  int* actArr = (int*)(partials0 + NBLK);        // 16 ints
  float* buf1 = out + (size_t)BB * NOB;          // s-slice of d_out: s1 (then s3,..)

  fused_kernel<<<NBLK, TPB, 0, stream>>>(x, dirs, obs, Wr, Win, Wout,
                                         buf0, buf1, scl0, scl1, partials0, partials);
  resolve_kernel<<<NBLK, TPB, 0, stream>>>(buf0, buf1, scl0, scl1, Wr, Wout, Win,
                                           dirs, obs, partials0, partials, actArr, out);
  for (int k = 2; k < 10; ++k)
    step_kernel<<<NBLK, TPB, 0, stream>>>(buf0, buf1, scl0, scl1,
                                          Wr, Wout, Win, dirs, obs, partials, actArr, out, k);
  final_kernel<<<NBLK, TPB, 0, stream>>>(buf0, out, scl0, Wout, actArr);
}

// Round 13
// 141.518 us; speedup vs baseline: 1.7760x; 1.0567x over previous
//
#include <hip/hip_runtime.h>
#include <math.h>

#define BB 131072
#define HH 64
#define NOB 32
#define NDIRS 8
#define LR_IT 1e-3f
#define TOLV 1e-3f
#define EPSV 1e-6f
#define NBLK 512
#define TPB 256
#define WRS 68   // LDS row stride (floats) for Wr / WinT
#define WOS 36   // LDS row stride for WoutT
#define INV_BH (1.0f/8388608.0f)   // 1/(B*H)

// macro params must not be named x/y/z/w (textual expansion vs .x/.y/.z/.w members)
#define D16(pp, Wp, b) ((pp).x*(Wp)[(b)+0] + (pp).y*(Wp)[(b)+1] + (pp).z*(Wp)[(b)+2] + (pp).w*(Wp)[(b)+3])
#define DOT64P(Wp) (D16(p0,Wp,0)+D16(p1,Wp,4)+D16(p2,Wp,8)+D16(p3,Wp,12)+ \
                    D16(p4,Wp,16)+D16(p5,Wp,20)+D16(p6,Wp,24)+D16(p7,Wp,28)+ \
                    D16(p8,Wp,32)+D16(p9,Wp,36)+D16(p10,Wp,40)+D16(p11,Wp,44)+ \
                    D16(p12,Wp,48)+D16(p13,Wp,52)+D16(p14,Wp,56)+D16(p15,Wp,60))
#define LOADP(src) \
  float4 p0=(src)[0], p1=(src)[1], p2=(src)[2], p3=(src)[3], \
         p4=(src)[4], p5=(src)[5], p6=(src)[6], p7=(src)[7], \
         p8=(src)[8], p9=(src)[9], p10=(src)[10], p11=(src)[11], \
         p12=(src)[12], p13=(src)[13], p14=(src)[14], p15=(src)[15];
#define SUMSQ4(pp) ((pp).x*(pp).x + (pp).y*(pp).y + (pp).z*(pp).z + (pp).w*(pp).w)
#define SUM4(pp) ((pp).x + (pp).y + (pp).z + (pp).w)

// ---- LDS staging (stride = blockDim) ----
__device__ __forceinline__ void stage_wr(const float* __restrict__ Wr, float* wrl, int t, int bs) {
  const float4* g = (const float4*)Wr;           // Wr row-major [64][64]
  for (int i = t; i < 1024; i += bs) {
    int h = i >> 4, k4 = i & 15;
    *(float4*)&wrl[h * WRS + k4 * 4] = g[i];
  }
}
__device__ __forceinline__ void stage_wot(const float* __restrict__ Wout, float* wot, int t, int bs) {
  for (int i = t; i < NOB * HH; i += bs) {       // Wout [32][64] -> wot[h][o]
    int o = i >> 6, h = i & 63;
    wot[h * WOS + o] = Wout[i];
  }
}
__device__ __forceinline__ void stage_wint(const float* __restrict__ Win, float* wint, int t, int bs) {
  for (int i = t; i < HH * NDIRS; i += bs) {     // Win [64][8] -> wint[d][h]
    int h = i >> 3, d = i & 7;
    wint[d * WRS + h] = Win[i];
  }
}

// 256-thread (4-wave) block reduction; returns block total to ALL threads.
// Double-syncthreads internally -> safe back-to-back.
__device__ __forceinline__ float block_reduce_all(float v, float* red, int t) {
  #pragma unroll
  for (int off = 32; off > 0; off >>= 1) v += __shfl_down(v, off);
  __syncthreads();
  if ((t & 63) == 0) red[t >> 6] = v;
  __syncthreads();
  return red[0] + red[1] + red[2] + red[3];
}

// softmax(a_s * zz) -> jacobian-applied jp, in place (zz starts as raw logits)
#define SOFTJP(zzp, a_sv, obv) { \
  float m_ = -1e30f; \
  _Pragma("unroll") for (int o_=0;o_<NOB;++o_) m_ = fmaxf(m_, (zzp)[o_]); \
  float se_ = 0.f; \
  _Pragma("unroll") for (int o_=0;o_<NOB;++o_){ (zzp)[o_]=__expf((a_sv)*((zzp)[o_]-m_)); se_+=(zzp)[o_];} \
  float rse_ = 1.f/se_; float fob_=0.f, sf2_=0.f; \
  _Pragma("unroll") for (int o_=0;o_<NOB;++o_){ float f_=(zzp)[o_]*rse_; (zzp)[o_]=f_; sf2_+=f_*f_; fob_ += (o_==(obv))?f_:0.f;} \
  float fe_ = fob_ - sf2_; \
  _Pragma("unroll") for (int o_=0;o_<NOB;++o_){ float ep_=((o_==(obv))?1.f:0.f)-(zzp)[o_]; (zzp)[o_]=(zzp)[o_]*(ep_-fe_);} }

// preds = softmax(a_s * S_raw @ wot) -> out[:B*32]; a_s*S_raw -> out[B*32:]
__device__ __forceinline__ void final_write(
    int r, float a_s, const float* __restrict__ S, float* __restrict__ out,
    const float* wot) {
  const float4* __restrict__ sr4 = (const float4*)(S + (size_t)r * HH);
  float zz[NOB];
  #pragma unroll
  for (int o = 0; o < NOB; ++o) zz[o] = 0.f;
  #pragma unroll 4
  for (int h0 = 0; h0 < 16; ++h0) {
    float4 s4 = sr4[h0];
    const float* t0 = &wot[(h0 * 4 + 0) * WOS];
    const float* t1 = &wot[(h0 * 4 + 1) * WOS];
    const float* t2 = &wot[(h0 * 4 + 2) * WOS];
    const float* t3 = &wot[(h0 * 4 + 3) * WOS];
    #pragma unroll
    for (int o = 0; o < NOB; ++o)
      zz[o] += s4.x * t0[o] + s4.y * t1[o] + s4.z * t2[o] + s4.w * t3[o];
  }
  float m = -1e30f;
  #pragma unroll
  for (int o = 0; o < NOB; ++o) m = fmaxf(m, zz[o]);
  float se = 0.f;
  #pragma unroll
  for (int o = 0; o < NOB; ++o) { zz[o] = __expf(a_s * (zz[o] - m)); se += zz[o]; }
  float rse = 1.f / se;

  float4* po = (float4*)(out + (size_t)r * NOB);
  #pragma unroll
  for (int o4 = 0; o4 < 8; ++o4) {
    float4 f;
    f.x = zz[o4 * 4 + 0] * rse; f.y = zz[o4 * 4 + 1] * rse;
    f.z = zz[o4 * 4 + 2] * rse; f.w = zz[o4 * 4 + 3] * rse;
    po[o4] = f;
  }
  float4* so = (float4*)(out + (size_t)BB * NOB + (size_t)r * HH);
  #pragma unroll 4
  for (int h0 = 0; h0 < 16; ++h0) {
    float4 s4 = sr4[h0];    // in-place safe: same thread reads then writes same addr
    s4.x *= a_s; s4.y *= a_s; s4.z *= a_s; s4.w *= a_s;
    so[h0] = s4;
  }
}

// ---- fused: init + iteration-0 candidate, two passes with a live-range firewall ----
__global__ __launch_bounds__(TPB, 2) void fused_kernel(
    const float* __restrict__ x, const int* __restrict__ dirs,
    const int* __restrict__ obs,
    const float* __restrict__ Wr, const float* __restrict__ Win,
    const float* __restrict__ Wout,
    float* __restrict__ buf0, float* __restrict__ buf1,
    float* __restrict__ scl0, float* __restrict__ scl1,
    float* __restrict__ partials0, float* __restrict__ partials1)
{
  __shared__ float wrl[HH * WRS];
  __shared__ float wot[HH * WOS];
  __shared__ float wint[NDIRS * WRS];
  __shared__ float red[4];
  int t = threadIdx.x;
  stage_wr(Wr, wrl, t, TPB);
  stage_wot(Wout, wot, t, TPB);
  stage_wint(Win, wint, t, TPB);
  __syncthreads();

  int r = blockIdx.x * TPB + t;
  float gate0, a_s, sg;

  // ---- pass 1: x row in registers; s0 = relu(inv_x * x@WrT + drive) ----
  {
    const float4* __restrict__ xr = (const float4*)(x + (size_t)r * HH);
    LOADP(xr);
    float ssx = SUMSQ4(p0)+SUMSQ4(p1)+SUMSQ4(p2)+SUMSQ4(p3)+SUMSQ4(p4)+SUMSQ4(p5)+
                SUMSQ4(p6)+SUMSQ4(p7)+SUMSQ4(p8)+SUMSQ4(p9)+SUMSQ4(p10)+SUMSQ4(p11)+
                SUMSQ4(p12)+SUMSQ4(p13)+SUMSQ4(p14)+SUMSQ4(p15);
    float sx  = SUM4(p0)+SUM4(p1)+SUM4(p2)+SUM4(p3)+SUM4(p4)+SUM4(p5)+SUM4(p6)+SUM4(p7)+
                SUM4(p8)+SUM4(p9)+SUM4(p10)+SUM4(p11)+SUM4(p12)+SUM4(p13)+SUM4(p14)+SUM4(p15);
    float inv_x = 1.f / (sqrtf(ssx) + EPSV);
    int dir = dirs[r];

    float4* bo = (float4*)(buf0 + (size_t)r * HH);
    float ssg = 0.f, sgl = 0.f;
#define INIT_ONE(JJ, COMP) { \
      const float* wr_ = &wrl[(h0 * 4 + JJ) * WRS]; \
      u.COMP = fmaxf(fmaf(inv_x, DOT64P(wr_), d4.COMP), 0.f); }
    #pragma unroll 2
    for (int h0 = 0; h0 < 16; ++h0) {
      float4 d4 = *(const float4*)&wint[dir * WRS + h0 * 4];
      float4 u;
      INIT_ONE(0, x) INIT_ONE(1, y) INIT_ONE(2, z) INIT_ONE(3, w)
      bo[h0] = u;
      ssg += SUMSQ4(u); sgl += SUM4(u);
    }
    float inv_g = 1.f / (sqrtf(ssg) + EPSV);
    scl0[r] = inv_g;
    a_s = inv_g;
    sg = sgl;
    gate0 = inv_x * sx - inv_g * sgl;
  }

  __syncthreads();   // live-range firewall: x row dies here

  // ---- pass 2: logits from the hot buf0 row; softmax/jp; phase C ----
  int ob = obs[r];
  const float4* __restrict__ sr4 = (const float4*)(buf0 + (size_t)r * HH);
  float zz[NOB];
  #pragma unroll
  for (int o = 0; o < NOB; ++o) zz[o] = 0.f;
  #pragma unroll 4
  for (int h0 = 0; h0 < 16; ++h0) {
    float4 s4 = sr4[h0];
    const float* t0 = &wot[(h0 * 4 + 0) * WOS];
    const float* t1 = &wot[(h0 * 4 + 1) * WOS];
    const float* t2 = &wot[(h0 * 4 + 2) * WOS];
    const float* t3 = &wot[(h0 * 4 + 3) * WOS];
    #pragma unroll
    for (int o = 0; o < NOB; ++o)
      zz[o] += s4.x * t0[o] + s4.y * t1[o] + s4.z * t2[o] + s4.w * t3[o];
  }

  SOFTJP(zz, a_s, ob)

  // phase C: g = relu(prev@Wr+drive) == raw s0 at iteration 0; s = a_s * s0_raw
  float4* wo4 = (float4*)(buf1 + (size_t)r * HH);
  float ssu = 0.f, su = 0.f;
#define F0_ONE(JJ, COMP) { \
    const float* wt_ = &wot[(h0 * 4 + JJ) * WOS]; \
    float w_ = 0.f; \
    _Pragma("unroll") \
    for (int o = 0; o < NOB; ++o) w_ += zz[o] * wt_[o]; \
    float g_ = g4.COMP; \
    float sv_ = a_s * g_; \
    float uu_ = fmaf(LR_IT, g_ - sv_ + w_, sv_); \
    u.COMP = uu_; ssu += uu_ * uu_; su += uu_; }
  #pragma unroll 4
  for (int h0 = 0; h0 < 16; ++h0) {
    float4 g4 = sr4[h0];
    float4 u;
    F0_ONE(0, x) F0_ONE(1, y) F0_ONE(2, z) F0_ONE(3, w)
    wo4[h0] = u;
  }
  float inv_u = 1.f / (sqrtf(ssu) + EPSV);
  scl1[r] = inv_u;

  float tot0 = block_reduce_all(gate0, red, t);
  if (t == 0) partials0[blockIdx.x] = tot0;
  float tot1 = block_reduce_all(a_s * sg - inv_u * su, red, t);  // sum(s0n) - sum(s1n)
  if (t == 0) partials1[blockIdx.x] = tot1;
}

// ---- resolve: decide act0/act1 (grid-uniform), expected path writes output ----
__global__ __launch_bounds__(TPB, 2) void resolve_kernel(
    float* __restrict__ buf0, float* __restrict__ buf1,
    float* __restrict__ scl0, float* __restrict__ scl1,
    const float* __restrict__ Wr, const float* __restrict__ Wout,
    const float* __restrict__ Win,
    const int* __restrict__ dirs, const int* __restrict__ obs,
    const float* __restrict__ partials0, float* __restrict__ partials,
    int* __restrict__ actArr, float* __restrict__ out)
{
  __shared__ float wrl[HH * WRS];
  __shared__ float wot[HH * WOS];
  __shared__ float wint[NDIRS * WRS];
  __shared__ float red[4];
  int t = threadIdx.x;

  float t0v = block_reduce_all(partials0[t] + partials0[t + TPB], red, t);
  int act0 = (fabsf(t0v * INV_BH) > TOLV) ? 1 : 0;
  float t1v = block_reduce_all(partials[t] + partials[t + TPB], red, t);
  int act1 = (fabsf(t1v * INV_BH) > TOLV) ? 1 : 0;
  if (blockIdx.x == 0 && t == 0) actArr[1] = act0 && act1;

  int r = blockIdx.x * TPB + t;

  if (!act0) {
    // iteration 0 inactive: final = s0. Keep sticky invariant: partials <= tol.
    if (t == 0) partials[blockIdx.x] = partials0[blockIdx.x];
    stage_wot(Wout, wot, t, TPB);
    __syncthreads();
    final_write(r, scl0[r], buf0, out, wot);
    return;
  }
  if (!act1) {
    // expected path: iteration 1 inactive: final = s1 (buf1 is the out s-slice).
    stage_wot(Wout, wot, t, TPB);
    __syncthreads();
    final_write(r, scl1[r], buf1, out, wot);
    return;
  }

  // both active: run iteration 1 fully. S=buf1/scl1, P=buf0 (norm scl0), W=buf0/scl0.
  stage_wr(Wr, wrl, t, TPB);
  stage_wot(Wout, wot, t, TPB);
  stage_wint(Win, wint, t, TPB);
  __syncthreads();

  float a_s = scl1[r];
  float a_p = scl0[r];
  int ob = obs[r];
  int dir = dirs[r];
  const float4* __restrict__ sr4 = (const float4*)(buf1 + (size_t)r * HH);

  float zz[NOB];
  #pragma unroll
  for (int o = 0; o < NOB; ++o) zz[o] = 0.f;
  float sS = 0.f;
  #pragma unroll 2
  for (int h0 = 0; h0 < 16; ++h0) {
    float4 s4 = sr4[h0];
    sS += SUM4(s4);
    const float* t0 = &wot[(h0 * 4 + 0) * WOS];
    const float* t1 = &wot[(h0 * 4 + 1) * WOS];
    const float* t2 = &wot[(h0 * 4 + 2) * WOS];
    const float* t3 = &wot[(h0 * 4 + 3) * WOS];
    #pragma unroll
    for (int o = 0; o < NOB; ++o)
      zz[o] += s4.x * t0[o] + s4.y * t1[o] + s4.z * t2[o] + s4.w * t3[o];
  }
  SOFTJP(zz, a_s, ob)
  __syncthreads();   // live-range firewall

  const float4* __restrict__ pr4 = (const float4*)(buf0 + (size_t)r * HH);
  LOADP(pr4);
  float4* wo4 = (float4*)(buf0 + (size_t)r * HH);
  float ssu = 0.f, su = 0.f;
#define STEP_C_ONE(JJ, COMP) { \
    const float* wr_ = &wrl[(h0 * 4 + JJ) * WRS]; \
    float g_ = fmaxf(fmaf(a_p, DOT64P(wr_), d4.COMP), 0.f); \
    const float* wt_ = &wot[(h0 * 4 + JJ) * WOS]; \
    float w_ = 0.f; \
    _Pragma("unroll") \
    for (int o = 0; o < NOB; ++o) w_ += zz[o] * wt_[o]; \
    float sv_ = a_s * s4.COMP; \
    float uu_ = fmaf(LR_IT, g_ - sv_ + w_, sv_); \
    u.COMP = uu_; ssu += uu_ * uu_; su += uu_; }
  #pragma unroll 2
  for (int h0 = 0; h0 < 16; ++h0) {
    float4 s4 = sr4[h0];
    float4 d4 = *(const float4*)&wint[dir * WRS + h0 * 4];
    float4 u;
    STEP_C_ONE(0, x) STEP_C_ONE(1, y) STEP_C_ONE(2, z) STEP_C_ONE(3, w)
    wo4[h0] = u;
  }
  float inv_u = 1.f / (sqrtf(ssu) + EPSV);
  scl0[r] = inv_u;

  float tot2 = block_reduce_all(a_s * sS - inv_u * su, red, t);
  if (t == 0) partials[blockIdx.x] = tot2;
}

// ---- generic step k>=2: gate + (active | first-inactive final | no-op) ----
__global__ __launch_bounds__(TPB, 2) void step_kernel(
    float* __restrict__ buf0, float* __restrict__ buf1,
    float* __restrict__ scl0, float* __restrict__ scl1,
    const float* __restrict__ Wr, const float* __restrict__ Wout,
    const float* __restrict__ Win,
    const int* __restrict__ dirs, const int* __restrict__ obs,
    float* __restrict__ partials, int* __restrict__ actArr,
    float* __restrict__ out, int k)
{
  __shared__ float red[4];
  __shared__ float wrl[HH * WRS];
  __shared__ float wot[HH * WOS];
  __shared__ float wint[NDIRS * WRS];
  int t = threadIdx.x;

  float tot = block_reduce_all(partials[t] + partials[t + TPB], red, t);
  int active = (fabsf(tot * INV_BH) > TOLV) ? 1 : 0;
  if (blockIdx.x == 0 && t == 0) actArr[k] = active;

  int si = k & 1;
  int r = blockIdx.x * TPB + t;

  if (!active) {
    int first_inactive = actArr[k - 1];   // written by previous launch
    if (!first_inactive) return;          // uniform across grid
    stage_wot(Wout, wot, t, TPB);
    __syncthreads();
    const float* S   = si ? buf1 : buf0;
    const float* scl = si ? scl1 : scl0;
    final_write(r, scl[r], S, out, wot);
    return;
  }

  const float* S    = si ? buf1 : buf0;
  const float* sclS = si ? scl1 : scl0;
  float* W          = si ? buf0 : buf1;
  float* sclW       = si ? scl0 : scl1;

  stage_wr(Wr, wrl, t, TPB);
  stage_wot(Wout, wot, t, TPB);
  stage_wint(Win, wint, t, TPB);
  __syncthreads();

  float a_s = sclS[r];
  float a_p = sclW[r];
  int ob = obs[r];
  int dir = dirs[r];
  const float4* __restrict__ sr4 = (const float4*)(S + (size_t)r * HH);

  float zz[NOB];
  #pragma unroll
  for (int o = 0; o < NOB; ++o) zz[o] = 0.f;
  float sS = 0.f;
  #pragma unroll 2
  for (int h0 = 0; h0 < 16; ++h0) {
    float4 s4 = sr4[h0];
    sS += SUM4(s4);
    const float* t0 = &wot[(h0 * 4 + 0) * WOS];
    const float* t1 = &wot[(h0 * 4 + 1) * WOS];
    const float* t2 = &wot[(h0 * 4 + 2) * WOS];
    const float* t3 = &wot[(h0 * 4 + 3) * WOS];
    #pragma unroll
    for (int o = 0; o < NOB; ++o)
      zz[o] += s4.x * t0[o] + s4.y * t1[o] + s4.z * t2[o] + s4.w * t3[o];
  }
  SOFTJP(zz, a_s, ob)
  __syncthreads();   // live-range firewall

  const float4* __restrict__ pr4 = (const float4*)(W + (size_t)r * HH);
  LOADP(pr4);
  float4* wo4 = (float4*)(W + (size_t)r * HH);
  float ssu = 0.f, su = 0.f;
  #pragma unroll 2
  for (int h0 = 0; h0 < 16; ++h0) {
    float4 s4 = sr4[h0];
    float4 d4 = *(const float4*)&wint[dir * WRS + h0 * 4];
    float4 u;
    STEP_C_ONE(0, x) STEP_C_ONE(1, y) STEP_C_ONE(2, z) STEP_C_ONE(3, w)
    wo4[h0] = u;
  }
  float inv_u = 1.f / (sqrtf(ssu) + EPSV);
  sclW[r] = inv_u;

  float tot2 = block_reduce_all(a_s * sS - inv_u * su, red, t);
  if (t == 0) partials[blockIdx.x] = tot2;
}

// ---- tail: only fires when all 10 iterations were active ----
__global__ __launch_bounds__(TPB, 2) void final_kernel(
    const float* __restrict__ buf0, float* __restrict__ out,
    const float* __restrict__ scl0,
    const float* __restrict__ Wout, const int* __restrict__ actArr)
{
  if (actArr[9] == 0) return;
  __shared__ float wot[HH * WOS];
  int t = threadIdx.x;
  stage_wot(Wout, wot, t, TPB);
  __syncthreads();
  int r = blockIdx.x * TPB + t;   // 10 active iterations: s10 in buf0/scl0
  final_write(r, scl0[r], buf0, out, wot);
}

extern "C" void kernel_launch(void* const* d_in, const int* in_sizes, int n_in,
                              void* d_out, int out_size, void* d_ws, size_t ws_size,
                              hipStream_t stream) {
  const int* dirs = (const int*)d_in[0];
  const int* obs = (const int*)d_in[1];
  const float* x = (const float*)d_in[2];
  const float* Wr = (const float*)d_in[3];
  const float* Win = (const float*)d_in[4];
  const float* Wout = (const float*)d_in[5];
  float* out = (float*)d_out;
  float* ws = (float*)d_ws;

  float* buf0 = ws;                              // B*H raw state s0 (then s2,s4,..)
  float* scl0 = ws + (size_t)BB * HH;            // B
  float* scl1 = scl0 + BB;                       // B
  float* partials = scl1 + BB;                   // NBLK (gate for "current" iteration)
  float* partials0 = partials + NBLK;            // NBLK (gate0)
  int* actArr = (int*)(partials0 + NBLK);        // 16 ints
  float* buf1 = out + (size_t)BB * NOB;          // s-slice of d_out: s1 (then s3,..)

  fused_kernel<<<NBLK, TPB, 0, stream>>>(x, dirs, obs, Wr, Win, Wout,
                                         buf0, buf1, scl0, scl1, partials0, partials);
  resolve_kernel<<<NBLK, TPB, 0, stream>>>(buf0, buf1, scl0, scl1, Wr, Wout, Win,
                                           dirs, obs, partials0, partials, actArr, out);
  for (int k = 2; k < 10; ++k)
    step_kernel<<<NBLK, TPB, 0, stream>>>(buf0, buf1, scl0, scl1,
                                          Wr, Wout, Win, dirs, obs, partials, actArr, out, k);
  final_kernel<<<NBLK, TPB, 0, stream>>>(buf0, out, scl0, Wout, actArr);
}